// Round 3
// baseline (367.719 us; speedup 1.0000x reference)
//
#include <hip/hip_runtime.h>
#include <hip/hip_bf16.h>
#include <math.h>

// Problem constants
#define NTOK 32768      // B*L = 64*512
#define Hdim 256
#define Ldim 512
#define Bdim 64
#define NHEAD 4
#define HD 64
#define PADV 49999      // ITEMNUM-1

typedef __bf16 bf16x8 __attribute__((ext_vector_type(8)));
typedef __bf16 bf16x4 __attribute__((ext_vector_type(4)));
typedef float  f32x4  __attribute__((ext_vector_type(4)));
typedef unsigned short u16x8 __attribute__((ext_vector_type(8)));

union bf8u { bf16x8 v8; bf16x4 v4[2]; };

__device__ __forceinline__ unsigned short f2bf(float f) {
    unsigned int u = __float_as_uint(f);
    unsigned int r = (u + 0x7fffu + ((u >> 16) & 1u)) >> 16;
    return (unsigned short)r;
}
__device__ __forceinline__ float bf2f(unsigned short u) {
    return __uint_as_float(((unsigned int)u) << 16);
}

// async global->LDS, 16B per lane (dest must be wave-uniform base + lane*16)
__device__ __forceinline__ void gload16(const void* g, void* l) {
    __builtin_amdgcn_global_load_lds((const __attribute__((address_space(1))) unsigned int*)g,
                                     (__attribute__((address_space(3))) unsigned int*)l,
                                     16, 0, 0);
}

// ---------------- weight cast: 5 matrices x (2*256*256) f32 -> bf16 ----------------
__global__ __launch_bounds__(256)
void castw_kernel(const float* __restrict__ q, const float* __restrict__ k,
                  const float* __restrict__ v, const float* __restrict__ c1,
                  const float* __restrict__ c2, unsigned short* __restrict__ dst) {
    const float* srcs[5] = {q, k, v, c1, c2};
    const float* s = srcs[blockIdx.y];
    int idx = blockIdx.x * 1024 + threadIdx.x * 4;
    float4 f = *(const float4*)(s + idx);
    unsigned short* d = dst + (size_t)blockIdx.y * 131072 + idx;
    d[0] = f2bf(f.x); d[1] = f2bf(f.y); d[2] = f2bf(f.z); d[3] = f2bf(f.w);
}

// ---------------- prep + ln_attn[0] fused (wave per token), all-bf16 outputs ----------------
__global__ __launch_bounds__(256)
void prep_ln_kernel(const int* __restrict__ seqs_data, const float* __restrict__ seqs,
                    const int* __restrict__ position, const float* __restrict__ time_emb,
                    const float* __restrict__ pos_table, const float* __restrict__ gate_W,
                    const float* __restrict__ gate_b,
                    const float* __restrict__ lnG, const float* __restrict__ lnB,
                    unsigned short* __restrict__ Tbf,
                    unsigned short* __restrict__ QXbf,
                    unsigned short* __restrict__ VINbf,
                    float* __restrict__ gates, float* __restrict__ keepv) {
    int tok  = blockIdx.x * 4 + (threadIdx.x >> 6);
    int lane = threadIdx.x & 63;
    size_t off = (size_t)tok * Hdim + lane * 4;
    int pos = position[tok];
    float4 pe = *(const float4*)(pos_table + (size_t)pos * Hdim + lane * 4);
    float4 sq = *(const float4*)(seqs + off);
    float4 tm = *(const float4*)(time_emb + off);
    float keep = (seqs_data[tok] != PADV) ? 1.0f : 0.0f;
    float4 t = {tm.x + pe.x, tm.y + pe.y, tm.z + pe.z, tm.w + pe.w};
    float4 s = {(sq.x + pe.x) * keep, (sq.y + pe.y) * keep,
                (sq.z + pe.z) * keep, (sq.w + pe.w) * keep};
    ushort4 tb = {f2bf(t.x), f2bf(t.y), f2bf(t.z), f2bf(t.w)};
    *(ushort4*)(Tbf + off) = tb;
    float4 gw0 = *(const float4*)(gate_W + lane * 4);
    float4 gw1 = *(const float4*)(gate_W + Hdim + lane * 4);
    float r0 = s.x + s.y + s.z + s.w;
    float r1 = s.x * s.x + s.y * s.y + s.z * s.z + s.w * s.w;
    float r2 = t.x * gw0.x + t.y * gw0.y + t.z * gw0.z + t.w * gw0.w;
    float r3 = t.x * gw1.x + t.y * gw1.y + t.z * gw1.z + t.w * gw1.w;
#pragma unroll
    for (int o = 1; o < 64; o <<= 1) {
        r0 += __shfl_xor(r0, o, 64);
        r1 += __shfl_xor(r1, o, 64);
        r2 += __shfl_xor(r2, o, 64);
        r3 += __shfl_xor(r3, o, 64);
    }
    float mean = r0 * (1.0f / Hdim);
    float var  = fmaxf(r1 * (1.0f / Hdim) - mean * mean, 0.0f);
    float rstd = rsqrtf(var + 1e-8f);
    if (lane == 0) {
        gates[(size_t)tok * 2 + 0] = 1.0f / (1.0f + __expf(-(r2 + gate_b[0])));
        gates[(size_t)tok * 2 + 1] = 1.0f / (1.0f + __expf(-(r3 + gate_b[1])));
        keepv[tok] = keep;
    }
    float4 g4 = *(const float4*)(lnG + lane * 4);
    float4 b4 = *(const float4*)(lnB + lane * 4);
    float4 y = {(s.x - mean) * rstd * g4.x + b4.x, (s.y - mean) * rstd * g4.y + b4.y,
                (s.z - mean) * rstd * g4.z + b4.z, (s.w - mean) * rstd * g4.w + b4.w};
    ushort4 yb = {f2bf(y.x), f2bf(y.y), f2bf(y.z), f2bf(y.w)};
    *(ushort4*)(QXbf + off) = yb;
    ushort4 vb = {f2bf(s.x + t.x), f2bf(s.y + t.y), f2bf(s.z + t.z), f2bf(s.w + t.w)};
    *(ushort4*)(VINbf + off) = vb;
}

#define GBM 128
#define GBN 128
#define GBK 64

// staging with XOR-swizzled chunk mapping: LDS is linear (gload16 requirement);
// lane fetches global chunk (row=c>>3, col8 = (c&7) ^ (row&7)); frag reads at
// row r, col-group g live at slot g^(r&7) -> 16-lane frag reads spread across
// all 8 chunk slots = conflict-free (2-way only).
__device__ __forceinline__ void stage64(const unsigned short* __restrict__ src,
                                        size_t rowBase, __bf16* lds, int tid, int kc) {
#pragma unroll
    for (int it = 0; it < 4; ++it) {
        int c = tid + it * 256;
        int r = c >> 3, sub = c & 7;
        int g = sub ^ (r & 7);
        gload16(src + (rowBase + r) * Hdim + kc + g * 8, lds + c * 8);
    }
}
__device__ __forceinline__ bf16x8 frag64(const __bf16* lds, int r, int g) {
    return *(const bf16x8*)(lds + r * 64 + (g ^ (r & 7)) * 8);
}

// ---------------- merged q/k/v GEMM 128x128 BK=64: blockIdx.z selects operand set ----------------
__global__ __launch_bounds__(256)
void gemm_qkv_kernel(const unsigned short* __restrict__ QXbf,
                     const unsigned short* __restrict__ Tbf,
                     const unsigned short* __restrict__ VINbf,
                     const unsigned short* __restrict__ qW,
                     const unsigned short* __restrict__ kW,
                     const unsigned short* __restrict__ vW,
                     const float* __restrict__ qb, const float* __restrict__ kb,
                     const float* __restrict__ vb,
                     unsigned short* __restrict__ Qbf,
                     unsigned short* __restrict__ Kbf,
                     unsigned short* __restrict__ VT) {
    // As(16K)+Ws(16K) = 32K, union with Ct[128][136] = 34816
    __shared__ __align__(16) char smem[128 * 136 * 2];
    __bf16* As = (__bf16*)smem;
    __bf16* Ws = (__bf16*)(smem + 16384);
    __bf16 (*Ct)[136] = (__bf16 (*)[136])smem;
    int z = blockIdx.z;
    const unsigned short* A = (z == 0) ? QXbf : (z == 1) ? Tbf : VINbf;
    const unsigned short* W = (z == 0) ? qW : (z == 1) ? kW : vW;
    const float* bias       = (z == 0) ? qb : (z == 1) ? kb : vb;

    int tid = threadIdx.x, lane = tid & 63, w = tid >> 6;
    int wr = w >> 1, wc = w & 1;
    int m0 = blockIdx.y * GBM, n0 = blockIdx.x * GBN;
    f32x4 acc[4][4];
#pragma unroll
    for (int i = 0; i < 4; ++i)
#pragma unroll
        for (int j = 0; j < 4; ++j) acc[i][j] = (f32x4)(0.0f);
    int colq = lane & 15, kg = lane >> 4;   // kg in 0..3: col-group kq = kg*8
    for (int kc = 0; kc < Hdim; kc += GBK) {
        __syncthreads();
        stage64(A, m0, As, tid, kc);
        stage64(W, n0, Ws, tid, kc);
        __syncthreads();
        bf16x8 af[4][2], bfr[4][2];
#pragma unroll
        for (int i = 0; i < 4; ++i) {
            int r = wr * 64 + i * 16 + colq;
            af[i][0] = frag64(As, r, kg);
            af[i][1] = frag64(As, r, 4 + kg);
        }
#pragma unroll
        for (int j = 0; j < 4; ++j) {
            int r = wc * 64 + j * 16 + colq;
            bfr[j][0] = frag64(Ws, r, kg);
            bfr[j][1] = frag64(Ws, r, 4 + kg);
        }
#pragma unroll
        for (int i = 0; i < 4; ++i)
#pragma unroll
            for (int j = 0; j < 4; ++j) {
                acc[i][j] = __builtin_amdgcn_mfma_f32_16x16x32_bf16(af[i][0], bfr[j][0], acc[i][j], 0, 0, 0);
                acc[i][j] = __builtin_amdgcn_mfma_f32_16x16x32_bf16(af[i][1], bfr[j][1], acc[i][j], 0, 0, 0);
            }
    }
    int rowq = (lane >> 4) * 4;
    if (z < 2) {
        unsigned short* outBF = (z == 0) ? Qbf : Kbf;
#pragma unroll
        for (int i = 0; i < 4; ++i)
#pragma unroll
            for (int r = 0; r < 4; ++r) {
                int m = m0 + wr * 64 + i * 16 + rowq + r;
#pragma unroll
                for (int j = 0; j < 4; ++j) {
                    int n = n0 + wc * 64 + j * 16 + colq;
                    outBF[(size_t)m * Hdim + n] = f2bf(acc[i][j][r] + bias[n]);
                }
            }
    } else {
        __syncthreads();   // all frag reads done before Ct overwrites As/Ws
#pragma unroll
        for (int i = 0; i < 4; ++i)
#pragma unroll
            for (int r = 0; r < 4; ++r) {
                int ml = wr * 64 + i * 16 + rowq + r;
#pragma unroll
                for (int j = 0; j < 4; ++j) {
                    int nl = wc * 64 + j * 16 + colq;
                    Ct[nl][ml] = (__bf16)(acc[i][j][r] + bias[n0 + nl]);
                }
            }
        __syncthreads();
        int bb = m0 >> 9, l0 = m0 & 511;
#pragma unroll
        for (int it = 0; it < 8; ++it) {
            int c = tid + it * 256;
            int nl = c >> 4;
            int o8 = (c & 15) * 8;
            int n = n0 + nl;
            int hh = n >> 6, dd = n & 63;
            bf16x8 v = *(const bf16x8*)&Ct[nl][o8];
            *(bf16x8*)(VT + ((((size_t)bb * NHEAD + hh) * HD + dd) * Ldim + l0 + o8)) = v;
        }
    }
}

// ================== fused FFN: ln2 + c1(relu) + c2 + lnout, FULL weight in LDS ==================
// 64-row tiles: grid = NTOK/64 = 512 blocks, 256 threads (4 waves, each 64 rows x 64 cols).
// LDS = Abuf 32KB (xn -> h -> z) + Wst 128KB (ENTIRE weight matrix) = 163840 B (the 160KiB
// max; 1 block/CU). Weight staged ONCE per GEMM -> the K-loops run with ZERO barriers
// (pure ds_read+MFMA, fully compiler-pipelined). 5 barriers total vs ~20 before.
// Row stats via 32-lane shuffle broadcast (each 32-lane group owns a full 256-col row).
#define FBM 64
#define FFN_LDS (32768 + 131072)

// slot swizzle for a [*][256] bf16 row: col-chunk g (0..31) of row r lives at slot
// (g&24) | ((g&7)^(r&7)); involution, so stager fetches chunk (s&24)|((s&7)^(r&7))
// into linear slot s. 16-row frag reads spread across 8 16B slots (2-way = free).
__device__ __forceinline__ int swz(int r, int g) {
    return (g & 24) | ((g & 7) ^ (r & 7));
}

// stage a full 256x256 bf16 weight matrix into LDS (swizzled), 32 gload16/thread
__device__ __forceinline__ void ffn_stageW(const unsigned short* __restrict__ W,
                                           __bf16* Wst, int tid) {
#pragma unroll
    for (int it = 0; it < 32; ++it) {
        int c = tid + it * 256;          // 0..8191 chunks
        int r = c >> 5, s = c & 31;
        int g = (s & 24) | ((s & 7) ^ (r & 7));
        gload16(W + (size_t)r * Hdim + g * 8, Wst + c * 8);
    }
}

__device__ __forceinline__ bf16x8 fragW(const __bf16* buf, int row, int slot8) {
    return *(const bf16x8*)(buf + row * 256 + swz(row, slot8) * 8);
}

// barrier-free GEMM over K=256: A[64][256] (LDS, swizzled) x W^T[256][256] (LDS, swizzled)
__device__ __forceinline__ void ffn_gemm(const __bf16* Abuf, const __bf16* Wst,
                                         int w, int colq, int kg, f32x4 acc[4][4]) {
#pragma unroll
    for (int i = 0; i < 4; ++i)
#pragma unroll
        for (int j = 0; j < 4; ++j) acc[i][j] = (f32x4)(0.0f);
#pragma unroll
    for (int kc = 0; kc < Hdim; kc += 64) {
        bf16x8 af[4][2], bfr[4][2];
#pragma unroll
        for (int i = 0; i < 4; ++i) {
            int r = i * 16 + colq;
            af[i][0] = fragW(Abuf, r, (kc >> 3) + kg);
            af[i][1] = fragW(Abuf, r, (kc >> 3) + 4 + kg);
        }
#pragma unroll
        for (int j = 0; j < 4; ++j) {
            int n = w * 64 + j * 16 + colq;
            bfr[j][0] = fragW(Wst, n, (kc >> 3) + kg);
            bfr[j][1] = fragW(Wst, n, (kc >> 3) + 4 + kg);
        }
#pragma unroll
        for (int i = 0; i < 4; ++i)
#pragma unroll
            for (int j = 0; j < 4; ++j) {
                acc[i][j] = __builtin_amdgcn_mfma_f32_16x16x32_bf16(af[i][0], bfr[j][0], acc[i][j], 0, 0, 0);
                acc[i][j] = __builtin_amdgcn_mfma_f32_16x16x32_bf16(af[i][1], bfr[j][1], acc[i][j], 0, 0, 0);
            }
    }
}

__global__ __launch_bounds__(256)
void ffn_kernel(const unsigned short* __restrict__ Qx,      // Q (ln_attn out)
                const unsigned short* __restrict__ Qa,      // attention output
                const float* __restrict__ lnG, const float* __restrict__ lnB,   // ln_ffn[i]
                const unsigned short* __restrict__ c1Wb, const float* __restrict__ c1b,
                const unsigned short* __restrict__ c2Wb, const float* __restrict__ c2b,
                const float* __restrict__ keepv,
                const unsigned short* __restrict__ Tbf,
                const float* __restrict__ oG, const float* __restrict__ oB,     // next ln params
                float* __restrict__ outF,                   // i=1: f32 final output, else null
                unsigned short* __restrict__ QxOut,
                unsigned short* __restrict__ VINout) {
    extern __shared__ __align__(16) char smem[];
    __bf16* Abuf = (__bf16*)smem;              // 64x256 swizzled (xn -> h -> z)
    __bf16* Wst  = (__bf16*)(smem + 32768);    // 256x256 full weight (c1 then c2)

    int m0  = blockIdx.x * FBM;
    int tid = threadIdx.x, lane = tid & 63, w = tid >> 6;
    int colq = lane & 15, kg = lane >> 4;
    int rowq = kg * 4;

    ffn_stageW(c1Wb, Wst, tid);     // async; drains at B1

    // ---- phase 1: x = Q + attn_out; per-row LN via 32-lane shuffle; xn -> Abuf + regs ----
    u16x8 qvr[8], avr[8];
#pragma unroll
    for (int it = 0; it < 8; ++it) {
        int c = tid + it * 256;
        int r = c >> 5, g = c & 31;
        size_t off = (size_t)(m0 + r) * Hdim + g * 8;
        qvr[it] = *(const u16x8*)(Qx + off);
        avr[it] = *(const u16x8*)(Qa + off);
    }
    u16x8 xnreg[8];
#pragma unroll
    for (int it = 0; it < 8; ++it) {
        int c = tid + it * 256;
        int r = c >> 5, g = c & 31, col = g * 8;
        float x[8];
        float cs = 0.0f, cq = 0.0f;
#pragma unroll
        for (int j = 0; j < 8; ++j) {
            x[j] = bf2f(qvr[it][j]) + bf2f(avr[it][j]);
            cs += x[j]; cq += x[j] * x[j];
        }
#pragma unroll
        for (int o = 1; o < 32; o <<= 1) {
            cs += __shfl_xor(cs, o, 32);
            cq += __shfl_xor(cq, o, 32);
        }
        float mean = cs * (1.0f / Hdim);
        float var  = fmaxf(cq * (1.0f / Hdim) - mean * mean, 0.0f);
        float rstd = rsqrtf(var + 1e-8f);
        float4 g0 = *(const float4*)(lnG + col), g1 = *(const float4*)(lnG + col + 4);
        float4 b0 = *(const float4*)(lnB + col), b1 = *(const float4*)(lnB + col + 4);
        float gv[8] = {g0.x, g0.y, g0.z, g0.w, g1.x, g1.y, g1.z, g1.w};
        float bv[8] = {b0.x, b0.y, b0.z, b0.w, b1.x, b1.y, b1.z, b1.w};
        u16x8 xn;
#pragma unroll
        for (int j = 0; j < 8; ++j)
            xn[j] = f2bf((x[j] - mean) * rstd * gv[j] + bv[j]);
        xnreg[it] = xn;
        *(u16x8*)(Abuf + r * 256 + swz(r, g) * 8) = xn;
    }
    __syncthreads();   // B1: xn visible + c1W staged (vmcnt drain)

    // ---- GEMM1: h = relu(xn @ c1W^T + b1) -- barrier-free k-loop ----
    f32x4 acc[4][4];
    ffn_gemm(Abuf, Wst, w, colq, kg, acc);
    __syncthreads();   // B2: all waves' Abuf/Wst reads done
    ffn_stageW(c2Wb, Wst, tid);     // async; overlaps h writeback; drains at B3
    float bj[4];
#pragma unroll
    for (int j = 0; j < 4; ++j) bj[j] = c1b[w * 64 + j * 16 + colq];
#pragma unroll
    for (int i = 0; i < 4; ++i)
#pragma unroll
        for (int r = 0; r < 4; ++r) {
            int m = i * 16 + rowq + r;
#pragma unroll
            for (int j = 0; j < 4; ++j) {
                int n = w * 64 + j * 16 + colq;
                float v = fmaxf(acc[i][j][r] + bj[j], 0.0f);
                Abuf[m * 256 + swz(m, n >> 3) * 8 + (n & 7)] = (__bf16)v;
            }
        }
    __syncthreads();   // B3: h visible + c2W staged

    // ---- GEMM2: z = h @ c2W^T + b2 -- barrier-free k-loop ----
    ffn_gemm(Abuf, Wst, w, colq, kg, acc);
    __syncthreads();   // B4: all h reads done
#pragma unroll
    for (int j = 0; j < 4; ++j) bj[j] = c2b[w * 64 + j * 16 + colq];
#pragma unroll
    for (int i = 0; i < 4; ++i)
#pragma unroll
        for (int r = 0; r < 4; ++r) {
            int m = i * 16 + rowq + r;
#pragma unroll
            for (int j = 0; j < 4; ++j) {
                int n = w * 64 + j * 16 + colq;
                Abuf[m * 256 + swz(m, n >> 3) * 8 + (n & 7)] = (__bf16)(acc[i][j][r] + bj[j]);
            }
        }
    __syncthreads();   // B5: z visible

    // ---- phase 5: s = (z + xn)*keep; LN; outputs ----
    u16x8 zvr[8];
#pragma unroll
    for (int it = 0; it < 8; ++it) {
        int c = tid + it * 256;
        int r = c >> 5, g = c & 31;
        zvr[it] = *(const u16x8*)(Abuf + r * 256 + swz(r, g) * 8);
    }
#pragma unroll
    for (int it = 0; it < 8; ++it) {
        int c = tid + it * 256;
        int r = c >> 5, g = c & 31, col = g * 8;
        float kf = keepv[m0 + r];
        float sv[8];
        float cs = 0.0f, cq = 0.0f;
#pragma unroll
        for (int j = 0; j < 8; ++j) {
            sv[j] = (bf2f(zvr[it][j]) + bf2f(xnreg[it][j])) * kf;
            cs += sv[j]; cq += sv[j] * sv[j];
        }
#pragma unroll
        for (int o = 1; o < 32; o <<= 1) {
            cs += __shfl_xor(cs, o, 32);
            cq += __shfl_xor(cq, o, 32);
        }
        float mean = cs * (1.0f / Hdim);
        float var  = fmaxf(cq * (1.0f / Hdim) - mean * mean, 0.0f);
        float rstd = rsqrtf(var + 1e-8f);
        float4 g0 = *(const float4*)(oG + col), g1 = *(const float4*)(oG + col + 4);
        float4 b0 = *(const float4*)(oB + col), b1 = *(const float4*)(oB + col + 4);
        float gv[8] = {g0.x, g0.y, g0.z, g0.w, g1.x, g1.y, g1.z, g1.w};
        float bv[8] = {b0.x, b0.y, b0.z, b0.w, b1.x, b1.y, b1.z, b1.w};
        size_t off = (size_t)(m0 + r) * Hdim + col;
        float y[8];
#pragma unroll
        for (int j = 0; j < 8; ++j)
            y[j] = (sv[j] - mean) * rstd * gv[j] + bv[j];
        if (outF) {
            float4 o0 = {y[0], y[1], y[2], y[3]};
            float4 o1 = {y[4], y[5], y[6], y[7]};
            *(float4*)(outF + off)     = o0;
            *(float4*)(outF + off + 4) = o1;
        } else {
            u16x8 yb, vb;
            u16x8 tv = *(const u16x8*)(Tbf + off);
#pragma unroll
            for (int j = 0; j < 8; ++j) {
                yb[j] = f2bf(y[j]);
                vb[j] = f2bf(sv[j] + bf2f(tv[j]));
            }
            *(u16x8*)(QxOut + off)  = yb;
            *(u16x8*)(VINout + off) = vb;
        }
    }
}

// ---------------- persistent per-(b,h) attention, 12 waves, b64-aligned slim strides ----------------
#define AKS 68
#define AVS 516
#define APS 68
#define ATTN_LDS (512 * AKS * 2 + 64 * AVS * 2 + 192 * APS * 2)
__global__ __launch_bounds__(768, 1)
void attn_mfma_kernel(const unsigned short* __restrict__ Qg,
                      const unsigned short* __restrict__ Kg,
                      const unsigned short* __restrict__ VTg,
                      const float* __restrict__ gates,
                      unsigned short* __restrict__ Ob, int blk) {
    extern __shared__ __align__(16) char smem[];
    __bf16 (*Ks)[AKS]  = (__bf16 (*)[AKS])smem;
    __bf16 (*VTs)[AVS] = (__bf16 (*)[AVS])(smem + 512 * AKS * 2);
    __bf16 (*Ps)[APS]  = (__bf16 (*)[APS])(smem + 512 * AKS * 2 + 64 * AVS * 2);
    int h = blockIdx.x & 3, b = blockIdx.x >> 2;
    int tid = threadIdx.x, lane = tid & 63, w = tid >> 6;
    int colq = lane & 15, grp = lane >> 4;
    int rowq = grp * 4, kq = grp * 8;

    size_t baseK = (size_t)b * Ldim * Hdim + h * HD;
    for (int c = tid; c < 4096; c += 768) {
        int r = c >> 3, o = (c & 7) * 8;
        bf8u u;
        u.v8 = *(const bf16x8*)(Kg + baseK + (size_t)r * Hdim + o);
        *(bf16x4*)&Ks[r][o]     = u.v4[0];
        *(bf16x4*)&Ks[r][o + 4] = u.v4[1];
    }
    size_t baseV = ((size_t)b * NHEAD + h) * HD * Ldim;
    for (int c = tid; c < 4096; c += 768) {
        int d = c >> 6, k = (c & 63) * 8;
        bf8u u;
        u.v8 = *(const bf16x8*)(VTg + baseV + (size_t)d * Ldim + k);
        *(bf16x4*)&VTs[d][k]     = u.v4[0];
        *(bf16x4*)&VTs[d][k + 4] = u.v4[1];
    }
    __syncthreads();   // the ONLY barrier

    const float lscale = 0.125f * 1.44269504f;
    int gl[3], ng;
    if (w < 4)      { gl[0] = w;     gl[1] = 8 + w;  gl[2] = 28 + w; ng = 3; }
    else if (w < 8) { gl[0] = w;     gl[1] = 8 + w;  gl[2] = 16 + w; ng = 3; }
    else            { gl[0] = 8 + w; gl[1] = 16 + w; gl[2] = 0;      ng = 2; }

    for (int gi = 0; gi < ng; ++gi) {
        int g = gl[gi];
        int q0 = g * 16;
        size_t qrow = (size_t)(b * Ldim + q0 + colq) * Hdim + h * HD;
        bf16x8 afq0 = *(const bf16x8*)(Qg + qrow + kq);
        bf16x8 afq1 = *(const bf16x8*)(Qg + qrow + 32 + kq);
        float gql[4];
#pragma unroll
        for (int r = 0; r < 4; ++r)
            gql[r] = gates[((size_t)b * Ldim + q0 + rowq + r) * 2 + blk] * lscale;

        float lrun[4] = {0.0f, 0.0f, 0.0f, 0.0f};
        f32x4 accO[4];
#pragma unroll
        for (int jd = 0; jd < 4; ++jd) accO[jd] = (f32x4)(0.0f);

        int nfull = g >> 2;
        for (int kt = 0; kt <= nfull; ++kt) {
            int k0 = kt * 64;
            bool diag = (kt == nfull);
            f32x4 sv[4];
#pragma unroll
            for (int j = 0; j < 4; ++j) sv[j] = (f32x4)(0.0f);
#pragma unroll
            for (int j = 0; j < 4; ++j) {
                int kr = k0 + j * 16 + colq;
                bf8u b0, b1;
                b0.v4[0] = *(const bf16x4*)&Ks[kr][kq];
                b0.v4[1] = *(const bf16x4*)&Ks[kr][kq + 4];
                b1.v4[0] = *(const bf16x4*)&Ks[kr][32 + kq];
                b1.v4[1] = *(const bf16x4*)&Ks[kr][32 + kq + 4];
                sv[j] = __builtin_amdgcn_mfma_f32_16x16x32_bf16(afq0, b0.v8, sv[j], 0, 0, 0);
                sv[j] = __builtin_amdgcn_mfma_f32_16x16x32_bf16(afq1, b1.v8, sv[j], 0, 0, 0);
            }
            float gkv[4];
#pragma unroll
            for (int j = 0; j < 4; ++j)
                gkv[j] = gates[((size_t)b * Ldim + k0 + j * 16 + colq) * 2 + blk];
#pragma unroll
            for (int r = 0; r < 4; ++r) {
                float su = 0.0f;
                float p4[4];
                if (diag) {
                    int qg = q0 + rowq + r;
#pragma unroll
                    for (int j = 0; j < 4; ++j) {
                        float v = sv[j][r] * gql[r] * gkv[j];
                        v = (k0 + j * 16 + colq > qg) ? -1e38f : v;
                        float e = exp2f(v);
                        p4[j] = e;
                        su += e;
                    }
                } else {
#pragma unroll
                    for (int j = 0; j < 4; ++j) {
                        float e = exp2f(sv[j][r] * gql[r] * gkv[j]);
                        p4[j] = e;
                        su += e;
                    }
                }
#pragma unroll
                for (int off = 1; off < 16; off <<= 1)
                    su += __shfl_xor(su, off, 16);
                lrun[r] += su;
#pragma unroll
                for (int j = 0; j < 4; ++j)
                    Ps[w * 16 + rowq + r][j * 16 + colq] = (__bf16)p4[j];
            }
            bf8u a0, a1;
            a0.v4[0] = *(const bf16x4*)&Ps[w * 16 + colq][kq];
            a0.v4[1] = *(const bf16x4*)&Ps[w * 16 + colq][kq + 4];
            a1.v4[0] = *(const bf16x4*)&Ps[w * 16 + colq][32 + kq];
            a1.v4[1] = *(const bf16x4*)&Ps[w * 16 + colq][32 + kq + 4];
#pragma unroll
            for (int jd = 0; jd < 4; ++jd) {
                int vr = jd * 16 + colq;
                bf8u v0, v1;
                v0.v4[0] = *(const bf16x4*)&VTs[vr][k0 + kq];
                v0.v4[1] = *(const bf16x4*)&VTs[vr][k0 + kq + 4];
                v1.v4[0] = *(const bf16x4*)&VTs[vr][k0 + 32 + kq];
                v1.v4[1] = *(const bf16x4*)&VTs[vr][k0 + 32 + kq + 4];
                accO[jd] = __builtin_amdgcn_mfma_f32_16x16x32_bf16(a0.v8, v0.v8, accO[jd], 0, 0, 0);
                accO[jd] = __builtin_amdgcn_mfma_f32_16x16x32_bf16(a1.v8, v1.v8, accO[jd], 0, 0, 0);
            }
        }
#pragma unroll
        for (int r = 0; r < 4; ++r) {
            float inv = 1.0f / lrun[r];
#pragma unroll
            for (int jd = 0; jd < 4; ++jd)
                Ob[(size_t)(b * Ldim + q0 + rowq + r) * Hdim + h * HD + jd * 16 + colq] =
                    f2bf(accO[jd][r] * inv);
        }
    }
}

// ---------------- launcher ----------------
extern "C" void kernel_launch(void* const* d_in, const int* in_sizes, int n_in,
                              void* d_out, int out_size, void* d_ws, size_t ws_size,
                              hipStream_t stream) {
    const int*   seqs_data = (const int*)d_in[0];
    const float* seqs      = (const float*)d_in[1];
    const int*   position  = (const int*)d_in[2];
    const float* time_emb  = (const float*)d_in[3];
    const float* pos_table = (const float*)d_in[4];
    const float* gate_W    = (const float*)d_in[5];
    const float* gate_b    = (const float*)d_in[6];
    const float* ln_attn_g = (const float*)d_in[7];
    const float* ln_attn_b = (const float*)d_in[8];
    const float* qW        = (const float*)d_in[9];
    const float* qb        = (const float*)d_in[10];
    const float* kW        = (const float*)d_in[11];
    const float* kb        = (const float*)d_in[12];
    const float* vW        = (const float*)d_in[13];
    const float* vb        = (const float*)d_in[14];
    const float* ln_ffn_g  = (const float*)d_in[15];
    const float* ln_ffn_b  = (const float*)d_in[16];
    const float* c1W       = (const float*)d_in[17];
    const float* c1b       = (const float*)d_in[18];
    const float* c2W       = (const float*)d_in[19];
    const float* c2b       = (const float*)d_in[20];
    const float* last_g    = (const float*)d_in[21];
    const float* last_b    = (const float*)d_in[22];

    size_t BUF = (size_t)NTOK * Hdim;
    float* fws = (float*)d_ws;
    float* GATES = fws;                       // NTOK*2
    float* KEEP  = GATES + (size_t)NTOK * 2;  // NTOK
    unsigned short* bws   = (unsigned short*)(KEEP + NTOK);
    unsigned short* Tbf   = bws;
    unsigned short* QXbf  = Tbf + BUF;        // Q / next-Q (in place)
    unsigned short* VINbf = QXbf + BUF;
    unsigned short* HIDbf = VINbf + BUF;      // (unused, layout kept)
    unsigned short* Qbf   = HIDbf + BUF;
    unsigned short* Kbf   = Qbf + BUF;
    unsigned short* VTbf  = Kbf + BUF;        // V^T [B][NH][HD][L]
    unsigned short* QAbf  = VTbf + BUF;
    unsigned short* Zbf   = QAbf + BUF;       // (unused, layout kept)
    unsigned short* Wbf   = Zbf + BUF;
    size_t WB = (size_t)Hdim * Hdim;
    unsigned short* qWbf  = Wbf;
    unsigned short* kWbf  = Wbf + 2 * WB;
    unsigned short* vWbf  = Wbf + 4 * WB;
    unsigned short* c1Wbf = Wbf + 6 * WB;
    unsigned short* c2Wbf = Wbf + 8 * WB;

    castw_kernel<<<dim3(128, 5), 256, 0, stream>>>(qW, kW, vW, c1W, c2W, Wbf);
    prep_ln_kernel<<<NTOK / 4, 256, 0, stream>>>(seqs_data, seqs, position, time_emb,
                                                 pos_table, gate_W, gate_b,
                                                 ln_attn_g, ln_attn_b,
                                                 Tbf, QXbf, VINbf, GATES, KEEP);

    dim3 qkvgrid(Hdim / GBN, NTOK / GBM, 3);   // (2, 256, 3)
    for (int i = 0; i < 2; ++i) {
        gemm_qkv_kernel<<<qkvgrid, 256, 0, stream>>>(QXbf, Tbf, VINbf,
                                                     qWbf + i * WB, kWbf + i * WB, vWbf + i * WB,
                                                     qb + i * Hdim, kb + i * Hdim, vb + i * Hdim,
                                                     Qbf, Kbf, VTbf);
        attn_mfma_kernel<<<Bdim * NHEAD, 768, ATTN_LDS, stream>>>(Qbf, Kbf, VTbf, GATES, QAbf, i);
        ffn_kernel<<<NTOK / FBM, 256, FFN_LDS, stream>>>(
            QXbf, QAbf,
            ln_ffn_g + i * Hdim, ln_ffn_b + i * Hdim,
            c1Wbf + i * WB, c1b + i * Hdim,
            c2Wbf + i * WB, c2b + i * Hdim,
            KEEP, Tbf,
            (i == 0) ? ln_attn_g + Hdim : last_g,
            (i == 0) ? ln_attn_b + Hdim : last_b,
            (i == 0) ? nullptr : (float*)d_out,
            QXbf, VINbf);
    }
}

// Round 4
// 341.367 us; speedup vs baseline: 1.0772x; 1.0772x over previous
//
#include <hip/hip_runtime.h>
#include <hip/hip_bf16.h>
#include <math.h>

// Problem constants
#define NTOK 32768      // B*L = 64*512
#define Hdim 256
#define Ldim 512
#define Bdim 64
#define NHEAD 4
#define HD 64
#define PADV 49999      // ITEMNUM-1

typedef __bf16 bf16x8 __attribute__((ext_vector_type(8)));
typedef __bf16 bf16x4 __attribute__((ext_vector_type(4)));
typedef float  f32x4  __attribute__((ext_vector_type(4)));
typedef unsigned short u16x8 __attribute__((ext_vector_type(8)));

union bf8u { bf16x8 v8; bf16x4 v4[2]; };

__device__ __forceinline__ unsigned short f2bf(float f) {
    unsigned int u = __float_as_uint(f);
    unsigned int r = (u + 0x7fffu + ((u >> 16) & 1u)) >> 16;
    return (unsigned short)r;
}
__device__ __forceinline__ float bf2f(unsigned short u) {
    return __uint_as_float(((unsigned int)u) << 16);
}

// async global->LDS, 16B per lane (dest must be wave-uniform base + lane*16)
__device__ __forceinline__ void gload16(const void* g, void* l) {
    __builtin_amdgcn_global_load_lds((const __attribute__((address_space(1))) unsigned int*)g,
                                     (__attribute__((address_space(3))) unsigned int*)l,
                                     16, 0, 0);
}

// ---------------- weight cast: 5 matrices x (2*256*256) f32 -> bf16 ----------------
__global__ __launch_bounds__(256)
void castw_kernel(const float* __restrict__ q, const float* __restrict__ k,
                  const float* __restrict__ v, const float* __restrict__ c1,
                  const float* __restrict__ c2, unsigned short* __restrict__ dst) {
    const float* srcs[5] = {q, k, v, c1, c2};
    const float* s = srcs[blockIdx.y];
    int idx = blockIdx.x * 1024 + threadIdx.x * 4;
    float4 f = *(const float4*)(s + idx);
    unsigned short* d = dst + (size_t)blockIdx.y * 131072 + idx;
    d[0] = f2bf(f.x); d[1] = f2bf(f.y); d[2] = f2bf(f.z); d[3] = f2bf(f.w);
}

// ---------------- prep + ln_attn[0] fused (wave per token), all-bf16 outputs ----------------
__global__ __launch_bounds__(256)
void prep_ln_kernel(const int* __restrict__ seqs_data, const float* __restrict__ seqs,
                    const int* __restrict__ position, const float* __restrict__ time_emb,
                    const float* __restrict__ pos_table, const float* __restrict__ gate_W,
                    const float* __restrict__ gate_b,
                    const float* __restrict__ lnG, const float* __restrict__ lnB,
                    unsigned short* __restrict__ Tbf,
                    unsigned short* __restrict__ QXbf,
                    unsigned short* __restrict__ VINbf,
                    float* __restrict__ gates, float* __restrict__ keepv) {
    int tok  = blockIdx.x * 4 + (threadIdx.x >> 6);
    int lane = threadIdx.x & 63;
    size_t off = (size_t)tok * Hdim + lane * 4;
    int pos = position[tok];
    float4 pe = *(const float4*)(pos_table + (size_t)pos * Hdim + lane * 4);
    float4 sq = *(const float4*)(seqs + off);
    float4 tm = *(const float4*)(time_emb + off);
    float keep = (seqs_data[tok] != PADV) ? 1.0f : 0.0f;
    float4 t = {tm.x + pe.x, tm.y + pe.y, tm.z + pe.z, tm.w + pe.w};
    float4 s = {(sq.x + pe.x) * keep, (sq.y + pe.y) * keep,
                (sq.z + pe.z) * keep, (sq.w + pe.w) * keep};
    ushort4 tb = {f2bf(t.x), f2bf(t.y), f2bf(t.z), f2bf(t.w)};
    *(ushort4*)(Tbf + off) = tb;
    float4 gw0 = *(const float4*)(gate_W + lane * 4);
    float4 gw1 = *(const float4*)(gate_W + Hdim + lane * 4);
    float r0 = s.x + s.y + s.z + s.w;
    float r1 = s.x * s.x + s.y * s.y + s.z * s.z + s.w * s.w;
    float r2 = t.x * gw0.x + t.y * gw0.y + t.z * gw0.z + t.w * gw0.w;
    float r3 = t.x * gw1.x + t.y * gw1.y + t.z * gw1.z + t.w * gw1.w;
#pragma unroll
    for (int o = 1; o < 64; o <<= 1) {
        r0 += __shfl_xor(r0, o, 64);
        r1 += __shfl_xor(r1, o, 64);
        r2 += __shfl_xor(r2, o, 64);
        r3 += __shfl_xor(r3, o, 64);
    }
    float mean = r0 * (1.0f / Hdim);
    float var  = fmaxf(r1 * (1.0f / Hdim) - mean * mean, 0.0f);
    float rstd = rsqrtf(var + 1e-8f);
    if (lane == 0) {
        gates[(size_t)tok * 2 + 0] = 1.0f / (1.0f + __expf(-(r2 + gate_b[0])));
        gates[(size_t)tok * 2 + 1] = 1.0f / (1.0f + __expf(-(r3 + gate_b[1])));
        keepv[tok] = keep;
    }
    float4 g4 = *(const float4*)(lnG + lane * 4);
    float4 b4 = *(const float4*)(lnB + lane * 4);
    float4 y = {(s.x - mean) * rstd * g4.x + b4.x, (s.y - mean) * rstd * g4.y + b4.y,
                (s.z - mean) * rstd * g4.z + b4.z, (s.w - mean) * rstd * g4.w + b4.w};
    ushort4 yb = {f2bf(y.x), f2bf(y.y), f2bf(y.z), f2bf(y.w)};
    *(ushort4*)(QXbf + off) = yb;
    ushort4 vb = {f2bf(s.x + t.x), f2bf(s.y + t.y), f2bf(s.z + t.z), f2bf(s.w + t.w)};
    *(ushort4*)(VINbf + off) = vb;
}

#define GBM 128
#define GBN 128
#define GBK 64

// staging with XOR-swizzled chunk mapping: LDS is linear (gload16 requirement);
// lane fetches global chunk (row=c>>3, col8 = (c&7) ^ (row&7)); frag reads at
// row r, col-group g live at slot g^(r&7) -> 16-lane frag reads spread across
// all 8 chunk slots = conflict-free (2-way only).
__device__ __forceinline__ void stage64(const unsigned short* __restrict__ src,
                                        size_t rowBase, __bf16* lds, int tid, int kc) {
#pragma unroll
    for (int it = 0; it < 4; ++it) {
        int c = tid + it * 256;
        int r = c >> 3, sub = c & 7;
        int g = sub ^ (r & 7);
        gload16(src + (rowBase + r) * Hdim + kc + g * 8, lds + c * 8);
    }
}
__device__ __forceinline__ bf16x8 frag64(const __bf16* lds, int r, int g) {
    return *(const bf16x8*)(lds + r * 64 + (g ^ (r & 7)) * 8);
}

// ---------------- merged q/k/v GEMM 128x128 BK=64: blockIdx.z selects operand set ----------------
__global__ __launch_bounds__(256)
void gemm_qkv_kernel(const unsigned short* __restrict__ QXbf,
                     const unsigned short* __restrict__ Tbf,
                     const unsigned short* __restrict__ VINbf,
                     const unsigned short* __restrict__ qW,
                     const unsigned short* __restrict__ kW,
                     const unsigned short* __restrict__ vW,
                     const float* __restrict__ qb, const float* __restrict__ kb,
                     const float* __restrict__ vb,
                     unsigned short* __restrict__ Qbf,
                     unsigned short* __restrict__ Kbf,
                     unsigned short* __restrict__ VT) {
    // As(16K)+Ws(16K) = 32K, union with Ct[128][136] = 34816
    __shared__ __align__(16) char smem[128 * 136 * 2];
    __bf16* As = (__bf16*)smem;
    __bf16* Ws = (__bf16*)(smem + 16384);
    __bf16 (*Ct)[136] = (__bf16 (*)[136])smem;
    int z = blockIdx.z;
    const unsigned short* A = (z == 0) ? QXbf : (z == 1) ? Tbf : VINbf;
    const unsigned short* W = (z == 0) ? qW : (z == 1) ? kW : vW;
    const float* bias       = (z == 0) ? qb : (z == 1) ? kb : vb;

    int tid = threadIdx.x, lane = tid & 63, w = tid >> 6;
    int wr = w >> 1, wc = w & 1;
    int m0 = blockIdx.y * GBM, n0 = blockIdx.x * GBN;
    f32x4 acc[4][4];
#pragma unroll
    for (int i = 0; i < 4; ++i)
#pragma unroll
        for (int j = 0; j < 4; ++j) acc[i][j] = (f32x4)(0.0f);
    int colq = lane & 15, kg = lane >> 4;   // kg in 0..3: col-group kq = kg*8
    for (int kc = 0; kc < Hdim; kc += GBK) {
        __syncthreads();
        stage64(A, m0, As, tid, kc);
        stage64(W, n0, Ws, tid, kc);
        __syncthreads();
        bf16x8 af[4][2], bfr[4][2];
#pragma unroll
        for (int i = 0; i < 4; ++i) {
            int r = wr * 64 + i * 16 + colq;
            af[i][0] = frag64(As, r, kg);
            af[i][1] = frag64(As, r, 4 + kg);
        }
#pragma unroll
        for (int j = 0; j < 4; ++j) {
            int r = wc * 64 + j * 16 + colq;
            bfr[j][0] = frag64(Ws, r, kg);
            bfr[j][1] = frag64(Ws, r, 4 + kg);
        }
#pragma unroll
        for (int i = 0; i < 4; ++i)
#pragma unroll
            for (int j = 0; j < 4; ++j) {
                acc[i][j] = __builtin_amdgcn_mfma_f32_16x16x32_bf16(af[i][0], bfr[j][0], acc[i][j], 0, 0, 0);
                acc[i][j] = __builtin_amdgcn_mfma_f32_16x16x32_bf16(af[i][1], bfr[j][1], acc[i][j], 0, 0, 0);
            }
    }
    int rowq = (lane >> 4) * 4;
    if (z < 2) {
        unsigned short* outBF = (z == 0) ? Qbf : Kbf;
#pragma unroll
        for (int i = 0; i < 4; ++i)
#pragma unroll
            for (int r = 0; r < 4; ++r) {
                int m = m0 + wr * 64 + i * 16 + rowq + r;
#pragma unroll
                for (int j = 0; j < 4; ++j) {
                    int n = n0 + wc * 64 + j * 16 + colq;
                    outBF[(size_t)m * Hdim + n] = f2bf(acc[i][j][r] + bias[n]);
                }
            }
    } else {
        __syncthreads();   // all frag reads done before Ct overwrites As/Ws
#pragma unroll
        for (int i = 0; i < 4; ++i)
#pragma unroll
            for (int r = 0; r < 4; ++r) {
                int ml = wr * 64 + i * 16 + rowq + r;
#pragma unroll
                for (int j = 0; j < 4; ++j) {
                    int nl = wc * 64 + j * 16 + colq;
                    Ct[nl][ml] = (__bf16)(acc[i][j][r] + bias[n0 + nl]);
                }
            }
        __syncthreads();
        int bb = m0 >> 9, l0 = m0 & 511;
#pragma unroll
        for (int it = 0; it < 8; ++it) {
            int c = tid + it * 256;
            int nl = c >> 4;
            int o8 = (c & 15) * 8;
            int n = n0 + nl;
            int hh = n >> 6, dd = n & 63;
            bf16x8 v = *(const bf16x8*)&Ct[nl][o8];
            *(bf16x8*)(VT + ((((size_t)bb * NHEAD + hh) * HD + dd) * Ldim + l0 + o8)) = v;
        }
    }
}

// ================== fused FFN: ln2 + c1(relu) + c2 + lnout in one kernel ==================
// R1 structure (best measured) + double-buffered weight stage + 1 raw barrier per k-step.
// 128-row tiles: grid = 256 blocks, 512 threads (8 waves, 2x4 over 128x256 output).
// LDS = Abuf 64KB (xn -> h -> z) + Wst dbuf 2x32KB = 128KB -> 1 block/CU, 8 waves.
// k-loop: issue stage(k+1)->nxt at top (covered by frag reads + MFMA), end with
// explicit vmcnt(0) + raw s_barrier (drain AFTER the MFMAs, not before).
#define FBM 128
#define FFN_LDS (65536 + 32768 * 2)

// chunk-slot swizzle for a [*][256] bf16 row: chunk g (0..31) of row r lives at slot
// (g&24) | ((g&7)^(r&7)) -> 16-row frag reads spread across 8 16B slots (2-way = free).
__device__ __forceinline__ int swz(int r, int g) {
    return (g & 24) | ((g & 7) ^ (r & 7));
}

// stage W[0:256][kc:kc+64] (32KB, 2048 16B-chunks) with 512 threads = 4/thread
__device__ __forceinline__ void ffn_stageK(const unsigned short* __restrict__ W, int kc,
                                           __bf16* Wst, int tid) {
#pragma unroll
    for (int it = 0; it < 4; ++it) {
        int c = tid + it * 512;
        int r = c >> 3, sub = c & 7;
        int g = sub ^ (r & 7);
        gload16(W + (size_t)r * Hdim + kc + g * 8, Wst + c * 8);
    }
}

// Precondition: Wst0 holds W[:,0:64] and all waves are past a full barrier.
// Postcondition: all waves synced, all Abuf/Wst frag reads complete.
__device__ __forceinline__ void ffn_gemm(const unsigned short* __restrict__ W,
                                         const __bf16* Abuf, __bf16* Wst0, __bf16* Wst1,
                                         int tid, int wr, int wc, int colq, int kg,
                                         f32x4 acc[4][4]) {
#pragma unroll
    for (int i = 0; i < 4; ++i)
#pragma unroll
        for (int j = 0; j < 4; ++j) acc[i][j] = (f32x4)(0.0f);
#pragma unroll
    for (int kc = 0; kc < Hdim; kc += GBK) {
        const __bf16* cur = ((kc >> 6) & 1) ? Wst1 : Wst0;
        __bf16*       nxt = ((kc >> 6) & 1) ? Wst0 : Wst1;
        if (kc + GBK < Hdim) ffn_stageK(W, kc + GBK, nxt, tid);
        bf16x8 af[4][2], bfr[4][2];
#pragma unroll
        for (int i = 0; i < 4; ++i) {
            int r = wr * 64 + i * 16 + colq;
            af[i][0] = *(const bf16x8*)(Abuf + r * 256 + ((kc >> 3) | (kg ^ (r & 7))) * 8);
            af[i][1] = *(const bf16x8*)(Abuf + r * 256 + ((kc >> 3) | ((4 + kg) ^ (r & 7))) * 8);
        }
#pragma unroll
        for (int j = 0; j < 4; ++j) {
            int n = wc * 64 + j * 16 + colq;
            bfr[j][0] = frag64(cur, n, kg);
            bfr[j][1] = frag64(cur, n, 4 + kg);
        }
#pragma unroll
        for (int i = 0; i < 4; ++i)
#pragma unroll
            for (int j = 0; j < 4; ++j) {
                acc[i][j] = __builtin_amdgcn_mfma_f32_16x16x32_bf16(af[i][0], bfr[j][0], acc[i][j], 0, 0, 0);
                acc[i][j] = __builtin_amdgcn_mfma_f32_16x16x32_bf16(af[i][1], bfr[j][1], acc[i][j], 0, 0, 0);
            }
        // stage(k+1) must land before next iter's frag reads; drain after MFMAs.
        asm volatile("s_waitcnt vmcnt(0)" ::: "memory");
        __builtin_amdgcn_s_barrier();
        asm volatile("" ::: "memory");
    }
}

__global__ __launch_bounds__(512, 1)
void ffn_kernel(const unsigned short* __restrict__ Qx,      // Q (ln_attn out)
                const unsigned short* __restrict__ Qa,      // attention output
                const float* __restrict__ lnG, const float* __restrict__ lnB,   // ln_ffn[i]
                const unsigned short* __restrict__ c1Wb, const float* __restrict__ c1b,
                const unsigned short* __restrict__ c2Wb, const float* __restrict__ c2b,
                const float* __restrict__ keepv,
                const unsigned short* __restrict__ Tbf,
                const float* __restrict__ oG, const float* __restrict__ oB,     // next ln params
                float* __restrict__ outF,                   // i=1: f32 final output, else null
                unsigned short* __restrict__ QxOut,
                unsigned short* __restrict__ VINout) {
    extern __shared__ __align__(16) char smem[];
    __bf16* Abuf = (__bf16*)smem;                      // 128x256 swizzled (xn -> h -> z)
    __bf16* Wst0 = (__bf16*)(smem + 65536);            // 256x64 weight k-tile (buf 0)
    __bf16* Wst1 = (__bf16*)(smem + 65536 + 32768);    // buf 1

    int m0  = blockIdx.x * FBM;
    int tid = threadIdx.x, lane = tid & 63, w = tid >> 6;
    int wr = w >> 2, wc = w & 3;
    int colq = lane & 15, kg = lane >> 4;
    int rowq = kg * 4;

    ffn_stageK(c1Wb, 0, Wst0, tid);   // prefetch GEMM1 k=0; drains at B1

    // ---- phase 1: x = Q + attn_out; per-row LN via 32-lane shuffle; xn -> Abuf + regs ----
    u16x8 qvr[8], avr[8];
#pragma unroll
    for (int it = 0; it < 8; ++it) {
        int c = tid + it * 512;
        int r = c >> 5, g = c & 31;
        size_t off = (size_t)(m0 + r) * Hdim + g * 8;
        qvr[it] = *(const u16x8*)(Qx + off);
        avr[it] = *(const u16x8*)(Qa + off);
    }
    u16x8 xnreg[8];
#pragma unroll
    for (int it = 0; it < 8; ++it) {
        int c = tid + it * 512;
        int r = c >> 5, g = c & 31, col = g * 8;
        float x[8];
        float cs = 0.0f, cq = 0.0f;
#pragma unroll
        for (int j = 0; j < 8; ++j) {
            x[j] = bf2f(qvr[it][j]) + bf2f(avr[it][j]);
            cs += x[j]; cq += x[j] * x[j];
        }
#pragma unroll
        for (int o = 1; o < 32; o <<= 1) {
            cs += __shfl_xor(cs, o, 32);
            cq += __shfl_xor(cq, o, 32);
        }
        float mean = cs * (1.0f / Hdim);
        float var  = fmaxf(cq * (1.0f / Hdim) - mean * mean, 0.0f);
        float rstd = rsqrtf(var + 1e-8f);
        float4 g0 = *(const float4*)(lnG + col), g1 = *(const float4*)(lnG + col + 4);
        float4 b0 = *(const float4*)(lnB + col), b1 = *(const float4*)(lnB + col + 4);
        float gv[8] = {g0.x, g0.y, g0.z, g0.w, g1.x, g1.y, g1.z, g1.w};
        float bv[8] = {b0.x, b0.y, b0.z, b0.w, b1.x, b1.y, b1.z, b1.w};
        u16x8 xn;
#pragma unroll
        for (int j = 0; j < 8; ++j)
            xn[j] = f2bf((x[j] - mean) * rstd * gv[j] + bv[j]);
        xnreg[it] = xn;
        *(u16x8*)(Abuf + r * 256 + swz(r, g) * 8) = xn;
    }
    __syncthreads();   // B1: xn visible + c1W k=0 staged (full drain)

    // ---- GEMM1: h = relu(xn @ c1W^T + b1) ----
    f32x4 acc[4][4];
    ffn_gemm(c1Wb, Abuf, Wst0, Wst1, tid, wr, wc, colq, kg, acc);
    ffn_stageK(c2Wb, 0, Wst0, tid);   // prefetch GEMM2 k=0; covered by h writeback + B2
    float bj[4];
#pragma unroll
    for (int j = 0; j < 4; ++j) bj[j] = c1b[wc * 64 + j * 16 + colq];
#pragma unroll
    for (int i = 0; i < 4; ++i)
#pragma unroll
        for (int r = 0; r < 4; ++r) {
            int m = wr * 64 + i * 16 + rowq + r;
#pragma unroll
            for (int j = 0; j < 4; ++j) {
                int n = wc * 64 + j * 16 + colq;
                float v = fmaxf(acc[i][j][r] + bj[j], 0.0f);
                Abuf[m * 256 + swz(m, n >> 3) * 8 + (n & 7)] = (__bf16)v;
            }
        }
    __syncthreads();   // B2: h visible + c2W k=0 staged (full drain)

    // ---- GEMM2: z = h @ c2W^T + b2 ----
    ffn_gemm(c2Wb, Abuf, Wst0, Wst1, tid, wr, wc, colq, kg, acc);
#pragma unroll
    for (int j = 0; j < 4; ++j) bj[j] = c2b[wc * 64 + j * 16 + colq];
#pragma unroll
    for (int i = 0; i < 4; ++i)
#pragma unroll
        for (int r = 0; r < 4; ++r) {
            int m = wr * 64 + i * 16 + rowq + r;
#pragma unroll
            for (int j = 0; j < 4; ++j) {
                int n = wc * 64 + j * 16 + colq;
                Abuf[m * 256 + swz(m, n >> 3) * 8 + (n & 7)] = (__bf16)(acc[i][j][r] + bj[j]);
            }
        }
    __syncthreads();   // B3: z visible

    // ---- phase 5: s = (z + xn)*keep; LN; outputs ----
    u16x8 zvr[8];
#pragma unroll
    for (int it = 0; it < 8; ++it) {
        int c = tid + it * 512;
        int r = c >> 5, g = c & 31;
        zvr[it] = *(const u16x8*)(Abuf + r * 256 + swz(r, g) * 8);
    }
#pragma unroll
    for (int it = 0; it < 8; ++it) {
        int c = tid + it * 512;
        int r = c >> 5, g = c & 31, col = g * 8;
        float kf = keepv[m0 + r];
        float sv[8];
        float cs = 0.0f, cq = 0.0f;
#pragma unroll
        for (int j = 0; j < 8; ++j) {
            sv[j] = (bf2f(zvr[it][j]) + bf2f(xnreg[it][j])) * kf;
            cs += sv[j]; cq += sv[j] * sv[j];
        }
#pragma unroll
        for (int o = 1; o < 32; o <<= 1) {
            cs += __shfl_xor(cs, o, 32);
            cq += __shfl_xor(cq, o, 32);
        }
        float mean = cs * (1.0f / Hdim);
        float var  = fmaxf(cq * (1.0f / Hdim) - mean * mean, 0.0f);
        float rstd = rsqrtf(var + 1e-8f);
        float4 g0 = *(const float4*)(oG + col), g1 = *(const float4*)(oG + col + 4);
        float4 b0 = *(const float4*)(oB + col), b1 = *(const float4*)(oB + col + 4);
        float gv[8] = {g0.x, g0.y, g0.z, g0.w, g1.x, g1.y, g1.z, g1.w};
        float bv[8] = {b0.x, b0.y, b0.z, b0.w, b1.x, b1.y, b1.z, b1.w};
        size_t off = (size_t)(m0 + r) * Hdim + col;
        float y[8];
#pragma unroll
        for (int j = 0; j < 8; ++j)
            y[j] = (sv[j] - mean) * rstd * gv[j] + bv[j];
        if (outF) {
            float4 o0 = {y[0], y[1], y[2], y[3]};
            float4 o1 = {y[4], y[5], y[6], y[7]};
            *(float4*)(outF + off)     = o0;
            *(float4*)(outF + off + 4) = o1;
        } else {
            u16x8 yb, vb;
            u16x8 tv = *(const u16x8*)(Tbf + off);
#pragma unroll
            for (int j = 0; j < 8; ++j) {
                yb[j] = f2bf(y[j]);
                vb[j] = f2bf(sv[j] + bf2f(tv[j]));
            }
            *(u16x8*)(QxOut + off)  = yb;
            *(u16x8*)(VINout + off) = vb;
        }
    }
}

// ---------------- persistent per-(b,h) attention, 12 waves, b64-aligned slim strides ----------------
#define AKS 68
#define AVS 516
#define APS 68
#define ATTN_LDS (512 * AKS * 2 + 64 * AVS * 2 + 192 * APS * 2)
__global__ __launch_bounds__(768, 1)
void attn_mfma_kernel(const unsigned short* __restrict__ Qg,
                      const unsigned short* __restrict__ Kg,
                      const unsigned short* __restrict__ VTg,
                      const float* __restrict__ gates,
                      unsigned short* __restrict__ Ob, int blk) {
    extern __shared__ __align__(16) char smem[];
    __bf16 (*Ks)[AKS]  = (__bf16 (*)[AKS])smem;
    __bf16 (*VTs)[AVS] = (__bf16 (*)[AVS])(smem + 512 * AKS * 2);
    __bf16 (*Ps)[APS]  = (__bf16 (*)[APS])(smem + 512 * AKS * 2 + 64 * AVS * 2);
    int h = blockIdx.x & 3, b = blockIdx.x >> 2;
    int tid = threadIdx.x, lane = tid & 63, w = tid >> 6;
    int colq = lane & 15, grp = lane >> 4;
    int rowq = grp * 4, kq = grp * 8;

    size_t baseK = (size_t)b * Ldim * Hdim + h * HD;
    for (int c = tid; c < 4096; c += 768) {
        int r = c >> 3, o = (c & 7) * 8;
        bf8u u;
        u.v8 = *(const bf16x8*)(Kg + baseK + (size_t)r * Hdim + o);
        *(bf16x4*)&Ks[r][o]     = u.v4[0];
        *(bf16x4*)&Ks[r][o + 4] = u.v4[1];
    }
    size_t baseV = ((size_t)b * NHEAD + h) * HD * Ldim;
    for (int c = tid; c < 4096; c += 768) {
        int d = c >> 6, k = (c & 63) * 8;
        bf8u u;
        u.v8 = *(const bf16x8*)(VTg + baseV + (size_t)d * Ldim + k);
        *(bf16x4*)&VTs[d][k]     = u.v4[0];
        *(bf16x4*)&VTs[d][k + 4] = u.v4[1];
    }
    __syncthreads();   // the ONLY barrier

    const float lscale = 0.125f * 1.44269504f;
    int gl[3], ng;
    if (w < 4)      { gl[0] = w;     gl[1] = 8 + w;  gl[2] = 28 + w; ng = 3; }
    else if (w < 8) { gl[0] = w;     gl[1] = 8 + w;  gl[2] = 16 + w; ng = 3; }
    else            { gl[0] = 8 + w; gl[1] = 16 + w; gl[2] = 0;      ng = 2; }

    for (int gi = 0; gi < ng; ++gi) {
        int g = gl[gi];
        int q0 = g * 16;
        size_t qrow = (size_t)(b * Ldim + q0 + colq) * Hdim + h * HD;
        bf16x8 afq0 = *(const bf16x8*)(Qg + qrow + kq);
        bf16x8 afq1 = *(const bf16x8*)(Qg + qrow + 32 + kq);
        float gql[4];
#pragma unroll
        for (int r = 0; r < 4; ++r)
            gql[r] = gates[((size_t)b * Ldim + q0 + rowq + r) * 2 + blk] * lscale;

        float lrun[4] = {0.0f, 0.0f, 0.0f, 0.0f};
        f32x4 accO[4];
#pragma unroll
        for (int jd = 0; jd < 4; ++jd) accO[jd] = (f32x4)(0.0f);

        int nfull = g >> 2;
        for (int kt = 0; kt <= nfull; ++kt) {
            int k0 = kt * 64;
            bool diag = (kt == nfull);
            f32x4 sv[4];
#pragma unroll
            for (int j = 0; j < 4; ++j) sv[j] = (f32x4)(0.0f);
            __builtin_amdgcn_s_setprio(1);
#pragma unroll
            for (int j = 0; j < 4; ++j) {
                int kr = k0 + j * 16 + colq;
                bf8u b0, b1;
                b0.v4[0] = *(const bf16x4*)&Ks[kr][kq];
                b0.v4[1] = *(const bf16x4*)&Ks[kr][kq + 4];
                b1.v4[0] = *(const bf16x4*)&Ks[kr][32 + kq];
                b1.v4[1] = *(const bf16x4*)&Ks[kr][32 + kq + 4];
                sv[j] = __builtin_amdgcn_mfma_f32_16x16x32_bf16(afq0, b0.v8, sv[j], 0, 0, 0);
                sv[j] = __builtin_amdgcn_mfma_f32_16x16x32_bf16(afq1, b1.v8, sv[j], 0, 0, 0);
            }
            __builtin_amdgcn_s_setprio(0);
            float gkv[4];
#pragma unroll
            for (int j = 0; j < 4; ++j)
                gkv[j] = gates[((size_t)b * Ldim + k0 + j * 16 + colq) * 2 + blk];
#pragma unroll
            for (int r = 0; r < 4; ++r) {
                float su = 0.0f;
                float p4[4];
                if (diag) {
                    int qg = q0 + rowq + r;
#pragma unroll
                    for (int j = 0; j < 4; ++j) {
                        float v = sv[j][r] * gql[r] * gkv[j];
                        v = (k0 + j * 16 + colq > qg) ? -1e38f : v;
                        float e = exp2f(v);
                        p4[j] = e;
                        su += e;
                    }
                } else {
#pragma unroll
                    for (int j = 0; j < 4; ++j) {
                        float e = exp2f(sv[j][r] * gql[r] * gkv[j]);
                        p4[j] = e;
                        su += e;
                    }
                }
#pragma unroll
                for (int off = 1; off < 16; off <<= 1)
                    su += __shfl_xor(su, off, 16);
                lrun[r] += su;
#pragma unroll
                for (int j = 0; j < 4; ++j)
                    Ps[w * 16 + rowq + r][j * 16 + colq] = (__bf16)p4[j];
            }
            bf8u a0, a1;
            a0.v4[0] = *(const bf16x4*)&Ps[w * 16 + colq][kq];
            a0.v4[1] = *(const bf16x4*)&Ps[w * 16 + colq][kq + 4];
            a1.v4[0] = *(const bf16x4*)&Ps[w * 16 + colq][32 + kq];
            a1.v4[1] = *(const bf16x4*)&Ps[w * 16 + colq][32 + kq + 4];
            __builtin_amdgcn_s_setprio(1);
#pragma unroll
            for (int jd = 0; jd < 4; ++jd) {
                int vr = jd * 16 + colq;
                bf8u v0, v1;
                v0.v4[0] = *(const bf16x4*)&VTs[vr][k0 + kq];
                v0.v4[1] = *(const bf16x4*)&VTs[vr][k0 + kq + 4];
                v1.v4[0] = *(const bf16x4*)&VTs[vr][k0 + 32 + kq];
                v1.v4[1] = *(const bf16x4*)&VTs[vr][k0 + 32 + kq + 4];
                accO[jd] = __builtin_amdgcn_mfma_f32_16x16x32_bf16(a0.v8, v0.v8, accO[jd], 0, 0, 0);
                accO[jd] = __builtin_amdgcn_mfma_f32_16x16x32_bf16(a1.v8, v1.v8, accO[jd], 0, 0, 0);
            }
            __builtin_amdgcn_s_setprio(0);
        }
#pragma unroll
        for (int r = 0; r < 4; ++r) {
            float inv = 1.0f / lrun[r];
#pragma unroll
            for (int jd = 0; jd < 4; ++jd)
                Ob[(size_t)(b * Ldim + q0 + rowq + r) * Hdim + h * HD + jd * 16 + colq] =
                    f2bf(accO[jd][r] * inv);
        }
    }
}

// ---------------- launcher ----------------
extern "C" void kernel_launch(void* const* d_in, const int* in_sizes, int n_in,
                              void* d_out, int out_size, void* d_ws, size_t ws_size,
                              hipStream_t stream) {
    const int*   seqs_data = (const int*)d_in[0];
    const float* seqs      = (const float*)d_in[1];
    const int*   position  = (const int*)d_in[2];
    const float* time_emb  = (const float*)d_in[3];
    const float* pos_table = (const float*)d_in[4];
    const float* gate_W    = (const float*)d_in[5];
    const float* gate_b    = (const float*)d_in[6];
    const float* ln_attn_g = (const float*)d_in[7];
    const float* ln_attn_b = (const float*)d_in[8];
    const float* qW        = (const float*)d_in[9];
    const float* qb        = (const float*)d_in[10];
    const float* kW        = (const float*)d_in[11];
    const float* kb        = (const float*)d_in[12];
    const float* vW        = (const float*)d_in[13];
    const float* vb        = (const float*)d_in[14];
    const float* ln_ffn_g  = (const float*)d_in[15];
    const float* ln_ffn_b  = (const float*)d_in[16];
    const float* c1W       = (const float*)d_in[17];
    const float* c1b       = (const float*)d_in[18];
    const float* c2W       = (const float*)d_in[19];
    const float* c2b       = (const float*)d_in[20];
    const float* last_g    = (const float*)d_in[21];
    const float* last_b    = (const float*)d_in[22];

    size_t BUF = (size_t)NTOK * Hdim;
    float* fws = (float*)d_ws;
    float* GATES = fws;                       // NTOK*2
    float* KEEP  = GATES + (size_t)NTOK * 2;  // NTOK
    unsigned short* bws   = (unsigned short*)(KEEP + NTOK);
    unsigned short* Tbf   = bws;
    unsigned short* QXbf  = Tbf + BUF;        // Q / next-Q (in place)
    unsigned short* VINbf = QXbf + BUF;
    unsigned short* HIDbf = VINbf + BUF;      // (unused, layout kept)
    unsigned short* Qbf   = HIDbf + BUF;
    unsigned short* Kbf   = Qbf + BUF;
    unsigned short* VTbf  = Kbf + BUF;        // V^T [B][NH][HD][L]
    unsigned short* QAbf  = VTbf + BUF;
    unsigned short* Zbf   = QAbf + BUF;       // (unused, layout kept)
    unsigned short* Wbf   = Zbf + BUF;
    size_t WB = (size_t)Hdim * Hdim;
    unsigned short* qWbf  = Wbf;
    unsigned short* kWbf  = Wbf + 2 * WB;
    unsigned short* vWbf  = Wbf + 4 * WB;
    unsigned short* c1Wbf = Wbf + 6 * WB;
    unsigned short* c2Wbf = Wbf + 8 * WB;

    castw_kernel<<<dim3(128, 5), 256, 0, stream>>>(qW, kW, vW, c1W, c2W, Wbf);
    prep_ln_kernel<<<NTOK / 4, 256, 0, stream>>>(seqs_data, seqs, position, time_emb,
                                                 pos_table, gate_W, gate_b,
                                                 ln_attn_g, ln_attn_b,
                                                 Tbf, QXbf, VINbf, GATES, KEEP);

    dim3 qkvgrid(Hdim / GBN, NTOK / GBM, 3);   // (2, 256, 3)
    for (int i = 0; i < 2; ++i) {
        gemm_qkv_kernel<<<qkvgrid, 256, 0, stream>>>(QXbf, Tbf, VINbf,
                                                     qWbf + i * WB, kWbf + i * WB, vWbf + i * WB,
                                                     qb + i * Hdim, kb + i * Hdim, vb + i * Hdim,
                                                     Qbf, Kbf, VTbf);
        attn_mfma_kernel<<<Bdim * NHEAD, 768, ATTN_LDS, stream>>>(Qbf, Kbf, VTbf, GATES, QAbf, i);
        ffn_kernel<<<NTOK / FBM, 512, FFN_LDS, stream>>>(
            QXbf, QAbf,
            ln_ffn_g + i * Hdim, ln_ffn_b + i * Hdim,
            c1Wbf + i * WB, c1b + i * Hdim,
            c2Wbf + i * WB, c2b + i * Hdim,
            KEEP, Tbf,
            (i == 0) ? ln_attn_g + Hdim : last_g,
            (i == 0) ? ln_attn_b + Hdim : last_b,
            (i == 0) ? nullptr : (float*)d_out,
            QXbf, VINbf);
    }
}

// Round 5
// 332.698 us; speedup vs baseline: 1.1053x; 1.0261x over previous
//
#include <hip/hip_runtime.h>
#include <hip/hip_bf16.h>
#include <math.h>

// Problem constants
#define NTOK 32768      // B*L = 64*512
#define Hdim 256
#define Ldim 512
#define Bdim 64
#define NHEAD 4
#define HD 64
#define PADV 49999      // ITEMNUM-1

typedef __bf16 bf16x8 __attribute__((ext_vector_type(8)));
typedef __bf16 bf16x4 __attribute__((ext_vector_type(4)));
typedef float  f32x4  __attribute__((ext_vector_type(4)));
typedef unsigned short u16x8 __attribute__((ext_vector_type(8)));

union bf8u { bf16x8 v8; bf16x4 v4[2]; };

__device__ __forceinline__ unsigned short f2bf(float f) {
    unsigned int u = __float_as_uint(f);
    unsigned int r = (u + 0x7fffu + ((u >> 16) & 1u)) >> 16;
    return (unsigned short)r;
}
__device__ __forceinline__ float bf2f(unsigned short u) {
    return __uint_as_float(((unsigned int)u) << 16);
}

// async global->LDS, 16B per lane (dest must be wave-uniform base + lane*16)
__device__ __forceinline__ void gload16(const void* g, void* l) {
    __builtin_amdgcn_global_load_lds((const __attribute__((address_space(1))) unsigned int*)g,
                                     (__attribute__((address_space(3))) unsigned int*)l,
                                     16, 0, 0);
}

// ---------------- prep + ln_attn[0] fused (wave per token) + weight-cast tail blocks ----------------
__global__ __launch_bounds__(256)
void prep_ln_kernel(const int* __restrict__ seqs_data, const float* __restrict__ seqs,
                    const int* __restrict__ position, const float* __restrict__ time_emb,
                    const float* __restrict__ pos_table, const float* __restrict__ gate_W,
                    const float* __restrict__ gate_b,
                    const float* __restrict__ lnG, const float* __restrict__ lnB,
                    unsigned short* __restrict__ Tbf,
                    unsigned short* __restrict__ QXbf,
                    unsigned short* __restrict__ VINbf,
                    float* __restrict__ gates, float* __restrict__ keepv,
                    const float* __restrict__ qW, const float* __restrict__ kW,
                    const float* __restrict__ vW, const float* __restrict__ c1W,
                    const float* __restrict__ c2W, unsigned short* __restrict__ Wdst) {
    if (blockIdx.x >= NTOK / 4) {
        // ---- castw tail: 640 blocks, 5 matrices x 131072 f32 -> bf16 ----
        int id  = blockIdx.x - NTOK / 4;
        int mat = id >> 7, bx = id & 127;
        const float* srcs[5] = {qW, kW, vW, c1W, c2W};
        const float* s = srcs[mat];
        int idx = bx * 1024 + threadIdx.x * 4;
        float4 f = *(const float4*)(s + idx);
        unsigned short* d = Wdst + (size_t)mat * 131072 + idx;
        d[0] = f2bf(f.x); d[1] = f2bf(f.y); d[2] = f2bf(f.z); d[3] = f2bf(f.w);
        return;
    }
    int tok  = blockIdx.x * 4 + (threadIdx.x >> 6);
    int lane = threadIdx.x & 63;
    size_t off = (size_t)tok * Hdim + lane * 4;
    int pos = position[tok];
    float4 pe = *(const float4*)(pos_table + (size_t)pos * Hdim + lane * 4);
    float4 sq = *(const float4*)(seqs + off);
    float4 tm = *(const float4*)(time_emb + off);
    float keep = (seqs_data[tok] != PADV) ? 1.0f : 0.0f;
    float4 t = {tm.x + pe.x, tm.y + pe.y, tm.z + pe.z, tm.w + pe.w};
    float4 s = {(sq.x + pe.x) * keep, (sq.y + pe.y) * keep,
                (sq.z + pe.z) * keep, (sq.w + pe.w) * keep};
    ushort4 tb = {f2bf(t.x), f2bf(t.y), f2bf(t.z), f2bf(t.w)};
    *(ushort4*)(Tbf + off) = tb;
    float4 gw0 = *(const float4*)(gate_W + lane * 4);
    float4 gw1 = *(const float4*)(gate_W + Hdim + lane * 4);
    float r0 = s.x + s.y + s.z + s.w;
    float r1 = s.x * s.x + s.y * s.y + s.z * s.z + s.w * s.w;
    float r2 = t.x * gw0.x + t.y * gw0.y + t.z * gw0.z + t.w * gw0.w;
    float r3 = t.x * gw1.x + t.y * gw1.y + t.z * gw1.z + t.w * gw1.w;
#pragma unroll
    for (int o = 1; o < 64; o <<= 1) {
        r0 += __shfl_xor(r0, o, 64);
        r1 += __shfl_xor(r1, o, 64);
        r2 += __shfl_xor(r2, o, 64);
        r3 += __shfl_xor(r3, o, 64);
    }
    float mean = r0 * (1.0f / Hdim);
    float var  = fmaxf(r1 * (1.0f / Hdim) - mean * mean, 0.0f);
    float rstd = rsqrtf(var + 1e-8f);
    if (lane == 0) {
        gates[(size_t)tok * 2 + 0] = 1.0f / (1.0f + __expf(-(r2 + gate_b[0])));
        gates[(size_t)tok * 2 + 1] = 1.0f / (1.0f + __expf(-(r3 + gate_b[1])));
        keepv[tok] = keep;
    }
    float4 g4 = *(const float4*)(lnG + lane * 4);
    float4 b4 = *(const float4*)(lnB + lane * 4);
    float4 y = {(s.x - mean) * rstd * g4.x + b4.x, (s.y - mean) * rstd * g4.y + b4.y,
                (s.z - mean) * rstd * g4.z + b4.z, (s.w - mean) * rstd * g4.w + b4.w};
    ushort4 yb = {f2bf(y.x), f2bf(y.y), f2bf(y.z), f2bf(y.w)};
    *(ushort4*)(QXbf + off) = yb;
    ushort4 vb = {f2bf(s.x + t.x), f2bf(s.y + t.y), f2bf(s.z + t.z), f2bf(s.w + t.w)};
    *(ushort4*)(VINbf + off) = vb;
}

#define GBM 128
#define GBN 128
#define GBK 64

// staging with XOR-swizzled chunk mapping: LDS is linear (gload16 requirement);
// lane fetches global chunk (row=c>>3, col8 = (c&7) ^ (row&7)); frag reads at
// row r, col-group g live at slot g^(r&7) -> 16-lane frag reads spread across
// all 8 chunk slots = conflict-free (2-way only).
__device__ __forceinline__ void stage64(const unsigned short* __restrict__ src,
                                        size_t rowBase, __bf16* lds, int tid, int kc) {
#pragma unroll
    for (int it = 0; it < 4; ++it) {
        int c = tid + it * 256;
        int r = c >> 3, sub = c & 7;
        int g = sub ^ (r & 7);
        gload16(src + (rowBase + r) * Hdim + kc + g * 8, lds + c * 8);
    }
}
__device__ __forceinline__ bf16x8 frag64(const __bf16* lds, int r, int g) {
    return *(const bf16x8*)(lds + r * 64 + (g ^ (r & 7)) * 8);
}

// ---------------- merged q/k/v GEMM 128x128 BK=64: blockIdx.z selects operand set ----------------
__global__ __launch_bounds__(256)
void gemm_qkv_kernel(const unsigned short* __restrict__ QXbf,
                     const unsigned short* __restrict__ Tbf,
                     const unsigned short* __restrict__ VINbf,
                     const unsigned short* __restrict__ qW,
                     const unsigned short* __restrict__ kW,
                     const unsigned short* __restrict__ vW,
                     const float* __restrict__ qb, const float* __restrict__ kb,
                     const float* __restrict__ vb,
                     unsigned short* __restrict__ Qbf,
                     unsigned short* __restrict__ Kbf,
                     unsigned short* __restrict__ VT) {
    // As(16K)+Ws(16K) = 32K, union with Ct[128][136] = 34816
    __shared__ __align__(16) char smem[128 * 136 * 2];
    __bf16* As = (__bf16*)smem;
    __bf16* Ws = (__bf16*)(smem + 16384);
    __bf16 (*Ct)[136] = (__bf16 (*)[136])smem;
    int z = blockIdx.z;
    const unsigned short* A = (z == 0) ? QXbf : (z == 1) ? Tbf : VINbf;
    const unsigned short* W = (z == 0) ? qW : (z == 1) ? kW : vW;
    const float* bias       = (z == 0) ? qb : (z == 1) ? kb : vb;

    int tid = threadIdx.x, lane = tid & 63, w = tid >> 6;
    int wr = w >> 1, wc = w & 1;
    int m0 = blockIdx.y * GBM, n0 = blockIdx.x * GBN;
    f32x4 acc[4][4];
#pragma unroll
    for (int i = 0; i < 4; ++i)
#pragma unroll
        for (int j = 0; j < 4; ++j) acc[i][j] = (f32x4)(0.0f);
    int colq = lane & 15, kg = lane >> 4;   // kg in 0..3: col-group kq = kg*8
    for (int kc = 0; kc < Hdim; kc += GBK) {
        __syncthreads();
        stage64(A, m0, As, tid, kc);
        stage64(W, n0, Ws, tid, kc);
        __syncthreads();
        bf16x8 af[4][2], bfr[4][2];
#pragma unroll
        for (int i = 0; i < 4; ++i) {
            int r = wr * 64 + i * 16 + colq;
            af[i][0] = frag64(As, r, kg);
            af[i][1] = frag64(As, r, 4 + kg);
        }
#pragma unroll
        for (int j = 0; j < 4; ++j) {
            int r = wc * 64 + j * 16 + colq;
            bfr[j][0] = frag64(Ws, r, kg);
            bfr[j][1] = frag64(Ws, r, 4 + kg);
        }
#pragma unroll
        for (int i = 0; i < 4; ++i)
#pragma unroll
            for (int j = 0; j < 4; ++j) {
                acc[i][j] = __builtin_amdgcn_mfma_f32_16x16x32_bf16(af[i][0], bfr[j][0], acc[i][j], 0, 0, 0);
                acc[i][j] = __builtin_amdgcn_mfma_f32_16x16x32_bf16(af[i][1], bfr[j][1], acc[i][j], 0, 0, 0);
            }
    }
    int rowq = (lane >> 4) * 4;
    if (z < 2) {
        unsigned short* outBF = (z == 0) ? Qbf : Kbf;
#pragma unroll
        for (int i = 0; i < 4; ++i)
#pragma unroll
            for (int r = 0; r < 4; ++r) {
                int m = m0 + wr * 64 + i * 16 + rowq + r;
#pragma unroll
                for (int j = 0; j < 4; ++j) {
                    int n = n0 + wc * 64 + j * 16 + colq;
                    outBF[(size_t)m * Hdim + n] = f2bf(acc[i][j][r] + bias[n]);
                }
            }
    } else {
        __syncthreads();   // all frag reads done before Ct overwrites As/Ws
#pragma unroll
        for (int i = 0; i < 4; ++i)
#pragma unroll
            for (int r = 0; r < 4; ++r) {
                int ml = wr * 64 + i * 16 + rowq + r;
#pragma unroll
                for (int j = 0; j < 4; ++j) {
                    int nl = wc * 64 + j * 16 + colq;
                    Ct[nl][ml] = (__bf16)(acc[i][j][r] + bias[n0 + nl]);
                }
            }
        __syncthreads();
        int bb = m0 >> 9, l0 = m0 & 511;
#pragma unroll
        for (int it = 0; it < 8; ++it) {
            int c = tid + it * 256;
            int nl = c >> 4;
            int o8 = (c & 15) * 8;
            int n = n0 + nl;
            int hh = n >> 6, dd = n & 63;
            bf16x8 v = *(const bf16x8*)&Ct[nl][o8];
            *(bf16x8*)(VT + ((((size_t)bb * NHEAD + hh) * HD + dd) * Ldim + l0 + o8)) = v;
        }
    }
}

// ================== fused FFN: ln2 + c1(relu) + c2 + lnout in one kernel ==================
// 128-row tiles: grid = 256 blocks, 512 threads (8 waves, 2x4 over 128x256 output).
// LDS = Abuf 64KB (xn -> h -> z) + Wst dbuf 2x32KB = 128KB -> 1 block/CU, 8 waves.
// k-loop: issue stage(k+1)->nxt at top (covered by frag reads + MFMA), end with
// explicit vmcnt(0) + raw s_barrier (drain AFTER the MFMAs, not before).
#define FBM 128
#define FFN_LDS (65536 + 32768 * 2)

// chunk-slot swizzle for a [*][256] bf16 row: chunk g (0..31) of row r lives at slot
// (g&24) | ((g&7)^(r&7)) -> 16-row frag reads spread across 8 16B slots (2-way = free).
__device__ __forceinline__ int swz(int r, int g) {
    return (g & 24) | ((g & 7) ^ (r & 7));
}

// stage W[0:256][kc:kc+64] (32KB, 2048 16B-chunks) with 512 threads = 4/thread
__device__ __forceinline__ void ffn_stageK(const unsigned short* __restrict__ W, int kc,
                                           __bf16* Wst, int tid) {
#pragma unroll
    for (int it = 0; it < 4; ++it) {
        int c = tid + it * 512;
        int r = c >> 3, sub = c & 7;
        int g = sub ^ (r & 7);
        gload16(W + (size_t)r * Hdim + kc + g * 8, Wst + c * 8);
    }
}

// Precondition: Wst0 holds W[:,0:64] and all waves are past a full barrier.
// Postcondition: all waves synced, all Abuf/Wst frag reads complete.
__device__ __forceinline__ void ffn_gemm(const unsigned short* __restrict__ W,
                                         const __bf16* Abuf, __bf16* Wst0, __bf16* Wst1,
                                         int tid, int wr, int wc, int colq, int kg,
                                         f32x4 acc[4][4]) {
#pragma unroll
    for (int i = 0; i < 4; ++i)
#pragma unroll
        for (int j = 0; j < 4; ++j) acc[i][j] = (f32x4)(0.0f);
#pragma unroll
    for (int kc = 0; kc < Hdim; kc += GBK) {
        const __bf16* cur = ((kc >> 6) & 1) ? Wst1 : Wst0;
        __bf16*       nxt = ((kc >> 6) & 1) ? Wst0 : Wst1;
        if (kc + GBK < Hdim) ffn_stageK(W, kc + GBK, nxt, tid);
        bf16x8 af[4][2], bfr[4][2];
#pragma unroll
        for (int i = 0; i < 4; ++i) {
            int r = wr * 64 + i * 16 + colq;
            af[i][0] = *(const bf16x8*)(Abuf + r * 256 + ((kc >> 3) | (kg ^ (r & 7))) * 8);
            af[i][1] = *(const bf16x8*)(Abuf + r * 256 + ((kc >> 3) | ((4 + kg) ^ (r & 7))) * 8);
        }
#pragma unroll
        for (int j = 0; j < 4; ++j) {
            int n = wc * 64 + j * 16 + colq;
            bfr[j][0] = frag64(cur, n, kg);
            bfr[j][1] = frag64(cur, n, 4 + kg);
        }
#pragma unroll
        for (int i = 0; i < 4; ++i)
#pragma unroll
            for (int j = 0; j < 4; ++j) {
                acc[i][j] = __builtin_amdgcn_mfma_f32_16x16x32_bf16(af[i][0], bfr[j][0], acc[i][j], 0, 0, 0);
                acc[i][j] = __builtin_amdgcn_mfma_f32_16x16x32_bf16(af[i][1], bfr[j][1], acc[i][j], 0, 0, 0);
            }
        // stage(k+1) must land before next iter's frag reads; drain after MFMAs.
        asm volatile("s_waitcnt vmcnt(0)" ::: "memory");
        __builtin_amdgcn_s_barrier();
        asm volatile("" ::: "memory");
    }
}

__global__ __launch_bounds__(512, 1)
void ffn_kernel(const unsigned short* __restrict__ Qx,      // Q (ln_attn out)
                const unsigned short* __restrict__ Qa,      // attention output
                const float* __restrict__ lnG, const float* __restrict__ lnB,   // ln_ffn[i]
                const unsigned short* __restrict__ c1Wb, const float* __restrict__ c1b,
                const unsigned short* __restrict__ c2Wb, const float* __restrict__ c2b,
                const float* __restrict__ keepv,
                const unsigned short* __restrict__ Tbf,
                const float* __restrict__ oG, const float* __restrict__ oB,     // next ln params
                float* __restrict__ outF,                   // i=1: f32 final output, else null
                unsigned short* __restrict__ QxOut,
                unsigned short* __restrict__ VINout) {
    extern __shared__ __align__(16) char smem[];
    __bf16* Abuf = (__bf16*)smem;                      // 128x256 swizzled (xn -> h -> z)
    __bf16* Wst0 = (__bf16*)(smem + 65536);            // 256x64 weight k-tile (buf 0)
    __bf16* Wst1 = (__bf16*)(smem + 65536 + 32768);    // buf 1

    int m0  = blockIdx.x * FBM;
    int tid = threadIdx.x, lane = tid & 63, w = tid >> 6;
    int wr = w >> 2, wc = w & 3;
    int colq = lane & 15, kg = lane >> 4;
    int rowq = kg * 4;

    ffn_stageK(c1Wb, 0, Wst0, tid);   // prefetch GEMM1 k=0; drains at B1

    // ---- phase 1: x = Q + attn_out; per-row LN via 32-lane shuffle; xn -> Abuf + regs ----
    u16x8 qvr[8], avr[8];
#pragma unroll
    for (int it = 0; it < 8; ++it) {
        int c = tid + it * 512;
        int r = c >> 5, g = c & 31;
        size_t off = (size_t)(m0 + r) * Hdim + g * 8;
        qvr[it] = *(const u16x8*)(Qx + off);
        avr[it] = *(const u16x8*)(Qa + off);
    }
    u16x8 xnreg[8];
#pragma unroll
    for (int it = 0; it < 8; ++it) {
        int c = tid + it * 512;
        int r = c >> 5, g = c & 31, col = g * 8;
        float x[8];
        float cs = 0.0f, cq = 0.0f;
#pragma unroll
        for (int j = 0; j < 8; ++j) {
            x[j] = bf2f(qvr[it][j]) + bf2f(avr[it][j]);
            cs += x[j]; cq += x[j] * x[j];
        }
#pragma unroll
        for (int o = 1; o < 32; o <<= 1) {
            cs += __shfl_xor(cs, o, 32);
            cq += __shfl_xor(cq, o, 32);
        }
        float mean = cs * (1.0f / Hdim);
        float var  = fmaxf(cq * (1.0f / Hdim) - mean * mean, 0.0f);
        float rstd = rsqrtf(var + 1e-8f);
        float4 g0 = *(const float4*)(lnG + col), g1 = *(const float4*)(lnG + col + 4);
        float4 b0 = *(const float4*)(lnB + col), b1 = *(const float4*)(lnB + col + 4);
        float gv[8] = {g0.x, g0.y, g0.z, g0.w, g1.x, g1.y, g1.z, g1.w};
        float bv[8] = {b0.x, b0.y, b0.z, b0.w, b1.x, b1.y, b1.z, b1.w};
        u16x8 xn;
#pragma unroll
        for (int j = 0; j < 8; ++j)
            xn[j] = f2bf((x[j] - mean) * rstd * gv[j] + bv[j]);
        xnreg[it] = xn;
        *(u16x8*)(Abuf + r * 256 + swz(r, g) * 8) = xn;
    }
    __syncthreads();   // B1: xn visible + c1W k=0 staged (full drain)

    // ---- GEMM1: h = relu(xn @ c1W^T + b1) ----
    f32x4 acc[4][4];
    ffn_gemm(c1Wb, Abuf, Wst0, Wst1, tid, wr, wc, colq, kg, acc);
    ffn_stageK(c2Wb, 0, Wst0, tid);   // prefetch GEMM2 k=0; covered by h writeback + B2
    float bj[4];
#pragma unroll
    for (int j = 0; j < 4; ++j) bj[j] = c1b[wc * 64 + j * 16 + colq];
#pragma unroll
    for (int i = 0; i < 4; ++i)
#pragma unroll
        for (int r = 0; r < 4; ++r) {
            int m = wr * 64 + i * 16 + rowq + r;
#pragma unroll
            for (int j = 0; j < 4; ++j) {
                int n = wc * 64 + j * 16 + colq;
                float v = fmaxf(acc[i][j][r] + bj[j], 0.0f);
                Abuf[m * 256 + swz(m, n >> 3) * 8 + (n & 7)] = (__bf16)v;
            }
        }
    __syncthreads();   // B2: h visible + c2W k=0 staged (full drain)

    // ---- GEMM2: z = h @ c2W^T + b2 ----
    ffn_gemm(c2Wb, Abuf, Wst0, Wst1, tid, wr, wc, colq, kg, acc);
#pragma unroll
    for (int j = 0; j < 4; ++j) bj[j] = c2b[wc * 64 + j * 16 + colq];
#pragma unroll
    for (int i = 0; i < 4; ++i)
#pragma unroll
        for (int r = 0; r < 4; ++r) {
            int m = wr * 64 + i * 16 + rowq + r;
#pragma unroll
            for (int j = 0; j < 4; ++j) {
                int n = wc * 64 + j * 16 + colq;
                Abuf[m * 256 + swz(m, n >> 3) * 8 + (n & 7)] = (__bf16)(acc[i][j][r] + bj[j]);
            }
        }
    __syncthreads();   // B3: z visible

    // ---- phase 5: s = (z + xn)*keep; LN; outputs ----
    u16x8 zvr[8];
#pragma unroll
    for (int it = 0; it < 8; ++it) {
        int c = tid + it * 512;
        int r = c >> 5, g = c & 31;
        zvr[it] = *(const u16x8*)(Abuf + r * 256 + swz(r, g) * 8);
    }
#pragma unroll
    for (int it = 0; it < 8; ++it) {
        int c = tid + it * 512;
        int r = c >> 5, g = c & 31, col = g * 8;
        float kf = keepv[m0 + r];
        float sv[8];
        float cs = 0.0f, cq = 0.0f;
#pragma unroll
        for (int j = 0; j < 8; ++j) {
            sv[j] = (bf2f(zvr[it][j]) + bf2f(xnreg[it][j])) * kf;
            cs += sv[j]; cq += sv[j] * sv[j];
        }
#pragma unroll
        for (int o = 1; o < 32; o <<= 1) {
            cs += __shfl_xor(cs, o, 32);
            cq += __shfl_xor(cq, o, 32);
        }
        float mean = cs * (1.0f / Hdim);
        float var  = fmaxf(cq * (1.0f / Hdim) - mean * mean, 0.0f);
        float rstd = rsqrtf(var + 1e-8f);
        float4 g0 = *(const float4*)(oG + col), g1 = *(const float4*)(oG + col + 4);
        float4 b0 = *(const float4*)(oB + col), b1 = *(const float4*)(oB + col + 4);
        float gv[8] = {g0.x, g0.y, g0.z, g0.w, g1.x, g1.y, g1.z, g1.w};
        float bv[8] = {b0.x, b0.y, b0.z, b0.w, b1.x, b1.y, b1.z, b1.w};
        size_t off = (size_t)(m0 + r) * Hdim + col;
        float y[8];
#pragma unroll
        for (int j = 0; j < 8; ++j)
            y[j] = (sv[j] - mean) * rstd * gv[j] + bv[j];
        if (outF) {
            float4 o0 = {y[0], y[1], y[2], y[3]};
            float4 o1 = {y[4], y[5], y[6], y[7]};
            *(float4*)(outF + off)     = o0;
            *(float4*)(outF + off + 4) = o1;
        } else {
            u16x8 yb, vb;
            u16x8 tv = *(const u16x8*)(Tbf + off);
#pragma unroll
            for (int j = 0; j < 8; ++j) {
                yb[j] = f2bf(y[j]);
                vb[j] = f2bf(sv[j] + bf2f(tv[j]));
            }
            *(u16x8*)(QxOut + off)  = yb;
            *(u16x8*)(VINout + off) = vb;
        }
    }
}

// ---------------- persistent per-(b,h) attention, 12 waves, b64-aligned slim strides ----------------
// Softmax denominator via MFMA row-sum: accL += mfma(P_frag, ones) -> accL[r] = rowsum(q=rowq+r)
// (C layout: row=(lane>>4)*4+reg=q, cols all equal). Replaces the 16-lane shuffle reduce.
#define AKS 68
#define AVS 516
#define APS 68
#define ATTN_LDS (512 * AKS * 2 + 64 * AVS * 2 + 192 * APS * 2)
__global__ __launch_bounds__(768, 1)
void attn_mfma_kernel(const unsigned short* __restrict__ Qg,
                      const unsigned short* __restrict__ Kg,
                      const unsigned short* __restrict__ VTg,
                      const float* __restrict__ gates,
                      unsigned short* __restrict__ Ob, int blk) {
    extern __shared__ __align__(16) char smem[];
    __bf16 (*Ks)[AKS]  = (__bf16 (*)[AKS])smem;
    __bf16 (*VTs)[AVS] = (__bf16 (*)[AVS])(smem + 512 * AKS * 2);
    __bf16 (*Ps)[APS]  = (__bf16 (*)[APS])(smem + 512 * AKS * 2 + 64 * AVS * 2);
    int h = blockIdx.x & 3, b = blockIdx.x >> 2;
    int tid = threadIdx.x, lane = tid & 63, w = tid >> 6;
    int colq = lane & 15, grp = lane >> 4;
    int rowq = grp * 4, kq = grp * 8;

    const __bf16 onev = (__bf16)1.0f;
    bf16x8 ones = {onev, onev, onev, onev, onev, onev, onev, onev};

    size_t baseK = (size_t)b * Ldim * Hdim + h * HD;
    for (int c = tid; c < 4096; c += 768) {
        int r = c >> 3, o = (c & 7) * 8;
        bf8u u;
        u.v8 = *(const bf16x8*)(Kg + baseK + (size_t)r * Hdim + o);
        *(bf16x4*)&Ks[r][o]     = u.v4[0];
        *(bf16x4*)&Ks[r][o + 4] = u.v4[1];
    }
    size_t baseV = ((size_t)b * NHEAD + h) * HD * Ldim;
    for (int c = tid; c < 4096; c += 768) {
        int d = c >> 6, k = (c & 63) * 8;
        bf8u u;
        u.v8 = *(const bf16x8*)(VTg + baseV + (size_t)d * Ldim + k);
        *(bf16x4*)&VTs[d][k]     = u.v4[0];
        *(bf16x4*)&VTs[d][k + 4] = u.v4[1];
    }
    __syncthreads();   // the ONLY barrier

    const float lscale = 0.125f * 1.44269504f;
    int gl[3], ng;
    if (w < 4)      { gl[0] = w;     gl[1] = 8 + w;  gl[2] = 28 + w; ng = 3; }
    else if (w < 8) { gl[0] = w;     gl[1] = 8 + w;  gl[2] = 16 + w; ng = 3; }
    else            { gl[0] = 8 + w; gl[1] = 16 + w; gl[2] = 0;      ng = 2; }

    for (int gi = 0; gi < ng; ++gi) {
        int g = gl[gi];
        int q0 = g * 16;
        size_t qrow = (size_t)(b * Ldim + q0 + colq) * Hdim + h * HD;
        bf16x8 afq0 = *(const bf16x8*)(Qg + qrow + kq);
        bf16x8 afq1 = *(const bf16x8*)(Qg + qrow + 32 + kq);
        float gql[4];
#pragma unroll
        for (int r = 0; r < 4; ++r)
            gql[r] = gates[((size_t)b * Ldim + q0 + rowq + r) * 2 + blk] * lscale;

        f32x4 accO[4];
        f32x4 accL = (f32x4)(0.0f);
#pragma unroll
        for (int jd = 0; jd < 4; ++jd) accO[jd] = (f32x4)(0.0f);

        int nfull = g >> 2;
        for (int kt = 0; kt <= nfull; ++kt) {
            int k0 = kt * 64;
            bool diag = (kt == nfull);
            f32x4 sv[4];
#pragma unroll
            for (int j = 0; j < 4; ++j) sv[j] = (f32x4)(0.0f);
            __builtin_amdgcn_s_setprio(1);
#pragma unroll
            for (int j = 0; j < 4; ++j) {
                int kr = k0 + j * 16 + colq;
                bf8u b0, b1;
                b0.v4[0] = *(const bf16x4*)&Ks[kr][kq];
                b0.v4[1] = *(const bf16x4*)&Ks[kr][kq + 4];
                b1.v4[0] = *(const bf16x4*)&Ks[kr][32 + kq];
                b1.v4[1] = *(const bf16x4*)&Ks[kr][32 + kq + 4];
                sv[j] = __builtin_amdgcn_mfma_f32_16x16x32_bf16(afq0, b0.v8, sv[j], 0, 0, 0);
                sv[j] = __builtin_amdgcn_mfma_f32_16x16x32_bf16(afq1, b1.v8, sv[j], 0, 0, 0);
            }
            __builtin_amdgcn_s_setprio(0);
            float gkv[4];
#pragma unroll
            for (int j = 0; j < 4; ++j)
                gkv[j] = gates[((size_t)b * Ldim + k0 + j * 16 + colq) * 2 + blk];
#pragma unroll
            for (int r = 0; r < 4; ++r) {
                float p4[4];
                if (diag) {
                    int qg = q0 + rowq + r;
#pragma unroll
                    for (int j = 0; j < 4; ++j) {
                        float v = sv[j][r] * gql[r] * gkv[j];
                        v = (k0 + j * 16 + colq > qg) ? -1e38f : v;
                        p4[j] = exp2f(v);
                    }
                } else {
#pragma unroll
                    for (int j = 0; j < 4; ++j)
                        p4[j] = exp2f(sv[j][r] * gql[r] * gkv[j]);
                }
#pragma unroll
                for (int j = 0; j < 4; ++j)
                    Ps[w * 16 + rowq + r][j * 16 + colq] = (__bf16)p4[j];
            }
            bf8u a0, a1;
            a0.v4[0] = *(const bf16x4*)&Ps[w * 16 + colq][kq];
            a0.v4[1] = *(const bf16x4*)&Ps[w * 16 + colq][kq + 4];
            a1.v4[0] = *(const bf16x4*)&Ps[w * 16 + colq][32 + kq];
            a1.v4[1] = *(const bf16x4*)&Ps[w * 16 + colq][32 + kq + 4];
            __builtin_amdgcn_s_setprio(1);
            accL = __builtin_amdgcn_mfma_f32_16x16x32_bf16(a0.v8, ones, accL, 0, 0, 0);
            accL = __builtin_amdgcn_mfma_f32_16x16x32_bf16(a1.v8, ones, accL, 0, 0, 0);
#pragma unroll
            for (int jd = 0; jd < 4; ++jd) {
                int vr = jd * 16 + colq;
                bf8u v0, v1;
                v0.v4[0] = *(const bf16x4*)&VTs[vr][k0 + kq];
                v0.v4[1] = *(const bf16x4*)&VTs[vr][k0 + kq + 4];
                v1.v4[0] = *(const bf16x4*)&VTs[vr][k0 + 32 + kq];
                v1.v4[1] = *(const bf16x4*)&VTs[vr][k0 + 32 + kq + 4];
                accO[jd] = __builtin_amdgcn_mfma_f32_16x16x32_bf16(a0.v8, v0.v8, accO[jd], 0, 0, 0);
                accO[jd] = __builtin_amdgcn_mfma_f32_16x16x32_bf16(a1.v8, v1.v8, accO[jd], 0, 0, 0);
            }
            __builtin_amdgcn_s_setprio(0);
        }
#pragma unroll
        for (int r = 0; r < 4; ++r) {
            float inv = 1.0f / accL[r];
#pragma unroll
            for (int jd = 0; jd < 4; ++jd)
                Ob[(size_t)(b * Ldim + q0 + rowq + r) * Hdim + h * HD + jd * 16 + colq] =
                    f2bf(accO[jd][r] * inv);
        }
    }
}

// ---------------- launcher ----------------
extern "C" void kernel_launch(void* const* d_in, const int* in_sizes, int n_in,
                              void* d_out, int out_size, void* d_ws, size_t ws_size,
                              hipStream_t stream) {
    const int*   seqs_data = (const int*)d_in[0];
    const float* seqs      = (const float*)d_in[1];
    const int*   position  = (const int*)d_in[2];
    const float* time_emb  = (const float*)d_in[3];
    const float* pos_table = (const float*)d_in[4];
    const float* gate_W    = (const float*)d_in[5];
    const float* gate_b    = (const float*)d_in[6];
    const float* ln_attn_g = (const float*)d_in[7];
    const float* ln_attn_b = (const float*)d_in[8];
    const float* qW        = (const float*)d_in[9];
    const float* qb        = (const float*)d_in[10];
    const float* kW        = (const float*)d_in[11];
    const float* kb        = (const float*)d_in[12];
    const float* vW        = (const float*)d_in[13];
    const float* vb        = (const float*)d_in[14];
    const float* ln_ffn_g  = (const float*)d_in[15];
    const float* ln_ffn_b  = (const float*)d_in[16];
    const float* c1W       = (const float*)d_in[17];
    const float* c1b       = (const float*)d_in[18];
    const float* c2W       = (const float*)d_in[19];
    const float* c2b       = (const float*)d_in[20];
    const float* last_g    = (const float*)d_in[21];
    const float* last_b    = (const float*)d_in[22];

    size_t BUF = (size_t)NTOK * Hdim;
    float* fws = (float*)d_ws;
    float* GATES = fws;                       // NTOK*2
    float* KEEP  = GATES + (size_t)NTOK * 2;  // NTOK
    unsigned short* bws   = (unsigned short*)(KEEP + NTOK);
    unsigned short* Tbf   = bws;
    unsigned short* QXbf  = Tbf + BUF;        // Q / next-Q (in place)
    unsigned short* VINbf = QXbf + BUF;
    unsigned short* HIDbf = VINbf + BUF;      // (unused, layout kept)
    unsigned short* Qbf   = HIDbf + BUF;
    unsigned short* Kbf   = Qbf + BUF;
    unsigned short* VTbf  = Kbf + BUF;        // V^T [B][NH][HD][L]
    unsigned short* QAbf  = VTbf + BUF;
    unsigned short* Zbf   = QAbf + BUF;       // (unused, layout kept)
    unsigned short* Wbf   = Zbf + BUF;
    size_t WB = (size_t)Hdim * Hdim;
    unsigned short* qWbf  = Wbf;
    unsigned short* kWbf  = Wbf + 2 * WB;
    unsigned short* vWbf  = Wbf + 4 * WB;
    unsigned short* c1Wbf = Wbf + 6 * WB;
    unsigned short* c2Wbf = Wbf + 8 * WB;

    // prep (8192 blocks) + fused castw tail (640 blocks)
    prep_ln_kernel<<<NTOK / 4 + 640, 256, 0, stream>>>(seqs_data, seqs, position, time_emb,
                                                       pos_table, gate_W, gate_b,
                                                       ln_attn_g, ln_attn_b,
                                                       Tbf, QXbf, VINbf, GATES, KEEP,
                                                       qW, kW, vW, c1W, c2W, Wbf);

    dim3 qkvgrid(Hdim / GBN, NTOK / GBM, 3);   // (2, 256, 3)
    for (int i = 0; i < 2; ++i) {
        gemm_qkv_kernel<<<qkvgrid, 256, 0, stream>>>(QXbf, Tbf, VINbf,
                                                     qWbf + i * WB, kWbf + i * WB, vWbf + i * WB,
                                                     qb + i * Hdim, kb + i * Hdim, vb + i * Hdim,
                                                     Qbf, Kbf, VTbf);
        attn_mfma_kernel<<<Bdim * NHEAD, 768, ATTN_LDS, stream>>>(Qbf, Kbf, VTbf, GATES, QAbf, i);
        ffn_kernel<<<NTOK / FBM, 512, FFN_LDS, stream>>>(
            QXbf, QAbf,
            ln_ffn_g + i * Hdim, ln_ffn_b + i * Hdim,
            c1Wbf + i * WB, c1b + i * Hdim,
            c2Wbf + i * WB, c2b + i * Hdim,
            KEEP, Tbf,
            (i == 0) ? ln_attn_g + Hdim : last_g,
            (i == 0) ? ln_attn_b + Hdim : last_b,
            (i == 0) ? nullptr : (float*)d_out,
            QXbf, VINbf);
    }
}

// Round 6
// 327.053 us; speedup vs baseline: 1.1243x; 1.0173x over previous
//
#include <hip/hip_runtime.h>
#include <hip/hip_bf16.h>
#include <math.h>

// Problem constants
#define NTOK 32768      // B*L = 64*512
#define Hdim 256
#define Ldim 512
#define Bdim 64
#define NHEAD 4
#define HD 64
#define PADV 49999      // ITEMNUM-1

typedef __bf16 bf16x8 __attribute__((ext_vector_type(8)));
typedef __bf16 bf16x4 __attribute__((ext_vector_type(4)));
typedef float  f32x4  __attribute__((ext_vector_type(4)));
typedef unsigned short u16x8 __attribute__((ext_vector_type(8)));

union bf8u { bf16x8 v8; bf16x4 v4[2]; };

__device__ __forceinline__ unsigned short f2bf(float f) {
    unsigned int u = __float_as_uint(f);
    unsigned int r = (u + 0x7fffu + ((u >> 16) & 1u)) >> 16;
    return (unsigned short)r;
}
__device__ __forceinline__ float bf2f(unsigned short u) {
    return __uint_as_float(((unsigned int)u) << 16);
}

// async global->LDS, 16B per lane (dest must be wave-uniform base + lane*16)
__device__ __forceinline__ void gload16(const void* g, void* l) {
    __builtin_amdgcn_global_load_lds((const __attribute__((address_space(1))) unsigned int*)g,
                                     (__attribute__((address_space(3))) unsigned int*)l,
                                     16, 0, 0);
}

// ---------------- prep + ln_attn[0] fused (wave per token) + weight-cast tail blocks ----------------
__global__ __launch_bounds__(256)
void prep_ln_kernel(const int* __restrict__ seqs_data, const float* __restrict__ seqs,
                    const int* __restrict__ position, const float* __restrict__ time_emb,
                    const float* __restrict__ pos_table, const float* __restrict__ gate_W,
                    const float* __restrict__ gate_b,
                    const float* __restrict__ lnG, const float* __restrict__ lnB,
                    unsigned short* __restrict__ Tbf,
                    unsigned short* __restrict__ QXbf,
                    unsigned short* __restrict__ VINbf,
                    float* __restrict__ gates, float* __restrict__ keepv,
                    const float* __restrict__ qW, const float* __restrict__ kW,
                    const float* __restrict__ vW, const float* __restrict__ c1W,
                    const float* __restrict__ c2W, unsigned short* __restrict__ Wdst) {
    if (blockIdx.x >= NTOK / 4) {
        // ---- castw tail: 640 blocks, 5 matrices x 131072 f32 -> bf16 ----
        int id  = blockIdx.x - NTOK / 4;
        int mat = id >> 7, bx = id & 127;
        const float* srcs[5] = {qW, kW, vW, c1W, c2W};
        const float* s = srcs[mat];
        int idx = bx * 1024 + threadIdx.x * 4;
        float4 f = *(const float4*)(s + idx);
        unsigned short* d = Wdst + (size_t)mat * 131072 + idx;
        d[0] = f2bf(f.x); d[1] = f2bf(f.y); d[2] = f2bf(f.z); d[3] = f2bf(f.w);
        return;
    }
    int tok  = blockIdx.x * 4 + (threadIdx.x >> 6);
    int lane = threadIdx.x & 63;
    size_t off = (size_t)tok * Hdim + lane * 4;
    int pos = position[tok];
    float4 pe = *(const float4*)(pos_table + (size_t)pos * Hdim + lane * 4);
    float4 sq = *(const float4*)(seqs + off);
    float4 tm = *(const float4*)(time_emb + off);
    float keep = (seqs_data[tok] != PADV) ? 1.0f : 0.0f;
    float4 t = {tm.x + pe.x, tm.y + pe.y, tm.z + pe.z, tm.w + pe.w};
    float4 s = {(sq.x + pe.x) * keep, (sq.y + pe.y) * keep,
                (sq.z + pe.z) * keep, (sq.w + pe.w) * keep};
    ushort4 tb = {f2bf(t.x), f2bf(t.y), f2bf(t.z), f2bf(t.w)};
    *(ushort4*)(Tbf + off) = tb;
    float4 gw0 = *(const float4*)(gate_W + lane * 4);
    float4 gw1 = *(const float4*)(gate_W + Hdim + lane * 4);
    float r0 = s.x + s.y + s.z + s.w;
    float r1 = s.x * s.x + s.y * s.y + s.z * s.z + s.w * s.w;
    float r2 = t.x * gw0.x + t.y * gw0.y + t.z * gw0.z + t.w * gw0.w;
    float r3 = t.x * gw1.x + t.y * gw1.y + t.z * gw1.z + t.w * gw1.w;
#pragma unroll
    for (int o = 1; o < 64; o <<= 1) {
        r0 += __shfl_xor(r0, o, 64);
        r1 += __shfl_xor(r1, o, 64);
        r2 += __shfl_xor(r2, o, 64);
        r3 += __shfl_xor(r3, o, 64);
    }
    float mean = r0 * (1.0f / Hdim);
    float var  = fmaxf(r1 * (1.0f / Hdim) - mean * mean, 0.0f);
    float rstd = rsqrtf(var + 1e-8f);
    if (lane == 0) {
        gates[(size_t)tok * 2 + 0] = 1.0f / (1.0f + __expf(-(r2 + gate_b[0])));
        gates[(size_t)tok * 2 + 1] = 1.0f / (1.0f + __expf(-(r3 + gate_b[1])));
        keepv[tok] = keep;
    }
    float4 g4 = *(const float4*)(lnG + lane * 4);
    float4 b4 = *(const float4*)(lnB + lane * 4);
    float4 y = {(s.x - mean) * rstd * g4.x + b4.x, (s.y - mean) * rstd * g4.y + b4.y,
                (s.z - mean) * rstd * g4.z + b4.z, (s.w - mean) * rstd * g4.w + b4.w};
    ushort4 yb = {f2bf(y.x), f2bf(y.y), f2bf(y.z), f2bf(y.w)};
    *(ushort4*)(QXbf + off) = yb;
    ushort4 vb = {f2bf(s.x + t.x), f2bf(s.y + t.y), f2bf(s.z + t.z), f2bf(s.w + t.w)};
    *(ushort4*)(VINbf + off) = vb;
}

#define GBM 128
#define GBN 128
#define GBK 64

// staging with XOR-swizzled chunk mapping: LDS is linear (gload16 requirement);
// lane fetches global chunk (row=c>>3, col8 = (c&7) ^ (row&7)); frag reads at
// row r, col-group g live at slot g^(r&7) -> 16-lane frag reads spread across
// all 8 chunk slots = conflict-free (2-way only).
__device__ __forceinline__ void stage64(const unsigned short* __restrict__ src,
                                        size_t rowBase, __bf16* lds, int tid, int kc) {
#pragma unroll
    for (int it = 0; it < 4; ++it) {
        int c = tid + it * 256;
        int r = c >> 3, sub = c & 7;
        int g = sub ^ (r & 7);
        gload16(src + (rowBase + r) * Hdim + kc + g * 8, lds + c * 8);
    }
}
__device__ __forceinline__ bf16x8 frag64(const __bf16* lds, int r, int g) {
    return *(const bf16x8*)(lds + r * 64 + (g ^ (r & 7)) * 8);
}

// ---------------- merged q/k/v GEMM 128x128 BK=64: blockIdx.z selects operand set ----------------
__global__ __launch_bounds__(256)
void gemm_qkv_kernel(const unsigned short* __restrict__ QXbf,
                     const unsigned short* __restrict__ Tbf,
                     const unsigned short* __restrict__ VINbf,
                     const unsigned short* __restrict__ qW,
                     const unsigned short* __restrict__ kW,
                     const unsigned short* __restrict__ vW,
                     const float* __restrict__ qb, const float* __restrict__ kb,
                     const float* __restrict__ vb,
                     unsigned short* __restrict__ Qbf,
                     unsigned short* __restrict__ Kbf,
                     unsigned short* __restrict__ VT) {
    // As(16K)+Ws(16K) = 32K, union with Ct[128][136] = 34816
    __shared__ __align__(16) char smem[128 * 136 * 2];
    __bf16* As = (__bf16*)smem;
    __bf16* Ws = (__bf16*)(smem + 16384);
    __bf16 (*Ct)[136] = (__bf16 (*)[136])smem;
    int z = blockIdx.z;
    const unsigned short* A = (z == 0) ? QXbf : (z == 1) ? Tbf : VINbf;
    const unsigned short* W = (z == 0) ? qW : (z == 1) ? kW : vW;
    const float* bias       = (z == 0) ? qb : (z == 1) ? kb : vb;

    int tid = threadIdx.x, lane = tid & 63, w = tid >> 6;
    int wr = w >> 1, wc = w & 1;
    int m0 = blockIdx.y * GBM, n0 = blockIdx.x * GBN;
    f32x4 acc[4][4];
#pragma unroll
    for (int i = 0; i < 4; ++i)
#pragma unroll
        for (int j = 0; j < 4; ++j) acc[i][j] = (f32x4)(0.0f);
    int colq = lane & 15, kg = lane >> 4;   // kg in 0..3: col-group kq = kg*8
    for (int kc = 0; kc < Hdim; kc += GBK) {
        __syncthreads();
        stage64(A, m0, As, tid, kc);
        stage64(W, n0, Ws, tid, kc);
        __syncthreads();
        bf16x8 af[4][2], bfr[4][2];
#pragma unroll
        for (int i = 0; i < 4; ++i) {
            int r = wr * 64 + i * 16 + colq;
            af[i][0] = frag64(As, r, kg);
            af[i][1] = frag64(As, r, 4 + kg);
        }
#pragma unroll
        for (int j = 0; j < 4; ++j) {
            int r = wc * 64 + j * 16 + colq;
            bfr[j][0] = frag64(Ws, r, kg);
            bfr[j][1] = frag64(Ws, r, 4 + kg);
        }
#pragma unroll
        for (int i = 0; i < 4; ++i)
#pragma unroll
            for (int j = 0; j < 4; ++j) {
                acc[i][j] = __builtin_amdgcn_mfma_f32_16x16x32_bf16(af[i][0], bfr[j][0], acc[i][j], 0, 0, 0);
                acc[i][j] = __builtin_amdgcn_mfma_f32_16x16x32_bf16(af[i][1], bfr[j][1], acc[i][j], 0, 0, 0);
            }
    }
    int rowq = (lane >> 4) * 4;
    if (z < 2) {
        unsigned short* outBF = (z == 0) ? Qbf : Kbf;
#pragma unroll
        for (int i = 0; i < 4; ++i)
#pragma unroll
            for (int r = 0; r < 4; ++r) {
                int m = m0 + wr * 64 + i * 16 + rowq + r;
#pragma unroll
                for (int j = 0; j < 4; ++j) {
                    int n = n0 + wc * 64 + j * 16 + colq;
                    outBF[(size_t)m * Hdim + n] = f2bf(acc[i][j][r] + bias[n]);
                }
            }
    } else {
        __syncthreads();   // all frag reads done before Ct overwrites As/Ws
#pragma unroll
        for (int i = 0; i < 4; ++i)
#pragma unroll
            for (int r = 0; r < 4; ++r) {
                int ml = wr * 64 + i * 16 + rowq + r;
#pragma unroll
                for (int j = 0; j < 4; ++j) {
                    int nl = wc * 64 + j * 16 + colq;
                    Ct[nl][ml] = (__bf16)(acc[i][j][r] + bias[n0 + nl]);
                }
            }
        __syncthreads();
        int bb = m0 >> 9, l0 = m0 & 511;
#pragma unroll
        for (int it = 0; it < 8; ++it) {
            int c = tid + it * 256;
            int nl = c >> 4;
            int o8 = (c & 15) * 8;
            int n = n0 + nl;
            int hh = n >> 6, dd = n & 63;
            bf16x8 v = *(const bf16x8*)&Ct[nl][o8];
            *(bf16x8*)(VT + ((((size_t)bb * NHEAD + hh) * HD + dd) * Ldim + l0 + o8)) = v;
        }
    }
}

// ================== fused FFN: ln2 + c1(relu) + c2 + lnout in one kernel ==================
// 128-row tiles: grid = 256 blocks, 512 threads (8 waves, 2x4 over 128x256 output).
// LDS = Abuf 64KB (xn -> h -> z) + Wst dbuf 2x32KB = 128KB -> 1 block/CU, 8 waves.
// k-loop: issue stage(k+1)->nxt at top (covered by frag reads + MFMA), end with
// explicit vmcnt(0) + raw s_barrier (drain AFTER the MFMAs, not before).
#define FBM 128
#define FFN_LDS (65536 + 32768 * 2)

// chunk-slot swizzle for a [*][256] bf16 row: chunk g (0..31) of row r lives at slot
// (g&24) | ((g&7)^(r&7)) -> 16-row frag reads spread across 8 16B slots (2-way = free).
__device__ __forceinline__ int swz(int r, int g) {
    return (g & 24) | ((g & 7) ^ (r & 7));
}

// stage W[0:256][kc:kc+64] (32KB, 2048 16B-chunks) with 512 threads = 4/thread
__device__ __forceinline__ void ffn_stageK(const unsigned short* __restrict__ W, int kc,
                                           __bf16* Wst, int tid) {
#pragma unroll
    for (int it = 0; it < 4; ++it) {
        int c = tid + it * 512;
        int r = c >> 3, sub = c & 7;
        int g = sub ^ (r & 7);
        gload16(W + (size_t)r * Hdim + kc + g * 8, Wst + c * 8);
    }
}

// Precondition: Wst0 holds W[:,0:64] and all waves are past a full barrier.
// Postcondition: all waves synced, all Abuf/Wst frag reads complete.
__device__ __forceinline__ void ffn_gemm(const unsigned short* __restrict__ W,
                                         const __bf16* Abuf, __bf16* Wst0, __bf16* Wst1,
                                         int tid, int wr, int wc, int colq, int kg,
                                         f32x4 acc[4][4]) {
#pragma unroll
    for (int i = 0; i < 4; ++i)
#pragma unroll
        for (int j = 0; j < 4; ++j) acc[i][j] = (f32x4)(0.0f);
#pragma unroll
    for (int kc = 0; kc < Hdim; kc += GBK) {
        const __bf16* cur = ((kc >> 6) & 1) ? Wst1 : Wst0;
        __bf16*       nxt = ((kc >> 6) & 1) ? Wst0 : Wst1;
        if (kc + GBK < Hdim) ffn_stageK(W, kc + GBK, nxt, tid);
        bf16x8 af[4][2], bfr[4][2];
#pragma unroll
        for (int i = 0; i < 4; ++i) {
            int r = wr * 64 + i * 16 + colq;
            af[i][0] = *(const bf16x8*)(Abuf + r * 256 + ((kc >> 3) | (kg ^ (r & 7))) * 8);
            af[i][1] = *(const bf16x8*)(Abuf + r * 256 + ((kc >> 3) | ((4 + kg) ^ (r & 7))) * 8);
        }
#pragma unroll
        for (int j = 0; j < 4; ++j) {
            int n = wc * 64 + j * 16 + colq;
            bfr[j][0] = frag64(cur, n, kg);
            bfr[j][1] = frag64(cur, n, 4 + kg);
        }
#pragma unroll
        for (int i = 0; i < 4; ++i)
#pragma unroll
            for (int j = 0; j < 4; ++j) {
                acc[i][j] = __builtin_amdgcn_mfma_f32_16x16x32_bf16(af[i][0], bfr[j][0], acc[i][j], 0, 0, 0);
                acc[i][j] = __builtin_amdgcn_mfma_f32_16x16x32_bf16(af[i][1], bfr[j][1], acc[i][j], 0, 0, 0);
            }
        // stage(k+1) must land before next iter's frag reads; drain after MFMAs.
        asm volatile("s_waitcnt vmcnt(0)" ::: "memory");
        __builtin_amdgcn_s_barrier();
        asm volatile("" ::: "memory");
    }
}

__global__ __launch_bounds__(512, 1)
void ffn_kernel(const unsigned short* __restrict__ Qx,      // Q (ln_attn out)
                const unsigned short* __restrict__ Qa,      // attention output
                const float* __restrict__ lnG, const float* __restrict__ lnB,   // ln_ffn[i]
                const unsigned short* __restrict__ c1Wb, const float* __restrict__ c1b,
                const unsigned short* __restrict__ c2Wb, const float* __restrict__ c2b,
                const float* __restrict__ keepv,
                const unsigned short* __restrict__ Tbf,
                const float* __restrict__ oG, const float* __restrict__ oB,     // next ln params
                float* __restrict__ outF,                   // i=1: f32 final output, else null
                unsigned short* __restrict__ QxOut,
                unsigned short* __restrict__ VINout) {
    extern __shared__ __align__(16) char smem[];
    __bf16* Abuf = (__bf16*)smem;                      // 128x256 swizzled (xn -> h -> z)
    __bf16* Wst0 = (__bf16*)(smem + 65536);            // 256x64 weight k-tile (buf 0)
    __bf16* Wst1 = (__bf16*)(smem + 65536 + 32768);    // buf 1

    int m0  = blockIdx.x * FBM;
    int tid = threadIdx.x, lane = tid & 63, w = tid >> 6;
    int wr = w >> 2, wc = w & 3;
    int colq = lane & 15, kg = lane >> 4;
    int rowq = kg * 4;

    ffn_stageK(c1Wb, 0, Wst0, tid);   // prefetch GEMM1 k=0; drains at B1

    // ---- phase 1: x = Q + attn_out; per-row LN via 32-lane shuffle; xn -> Abuf + regs ----
    u16x8 qvr[8], avr[8];
#pragma unroll
    for (int it = 0; it < 8; ++it) {
        int c = tid + it * 512;
        int r = c >> 5, g = c & 31;
        size_t off = (size_t)(m0 + r) * Hdim + g * 8;
        qvr[it] = *(const u16x8*)(Qx + off);
        avr[it] = *(const u16x8*)(Qa + off);
    }
    u16x8 xnreg[8];
#pragma unroll
    for (int it = 0; it < 8; ++it) {
        int c = tid + it * 512;
        int r = c >> 5, g = c & 31, col = g * 8;
        float x[8];
        float cs = 0.0f, cq = 0.0f;
#pragma unroll
        for (int j = 0; j < 8; ++j) {
            x[j] = bf2f(qvr[it][j]) + bf2f(avr[it][j]);
            cs += x[j]; cq += x[j] * x[j];
        }
#pragma unroll
        for (int o = 1; o < 32; o <<= 1) {
            cs += __shfl_xor(cs, o, 32);
            cq += __shfl_xor(cq, o, 32);
        }
        float mean = cs * (1.0f / Hdim);
        float var  = fmaxf(cq * (1.0f / Hdim) - mean * mean, 0.0f);
        float rstd = rsqrtf(var + 1e-8f);
        float4 g0 = *(const float4*)(lnG + col), g1 = *(const float4*)(lnG + col + 4);
        float4 b0 = *(const float4*)(lnB + col), b1 = *(const float4*)(lnB + col + 4);
        float gv[8] = {g0.x, g0.y, g0.z, g0.w, g1.x, g1.y, g1.z, g1.w};
        float bv[8] = {b0.x, b0.y, b0.z, b0.w, b1.x, b1.y, b1.z, b1.w};
        u16x8 xn;
#pragma unroll
        for (int j = 0; j < 8; ++j)
            xn[j] = f2bf((x[j] - mean) * rstd * gv[j] + bv[j]);
        xnreg[it] = xn;
        *(u16x8*)(Abuf + r * 256 + swz(r, g) * 8) = xn;
    }
    __syncthreads();   // B1: xn visible + c1W k=0 staged (full drain)

    // ---- GEMM1: h = relu(xn @ c1W^T + b1) ----
    f32x4 acc[4][4];
    ffn_gemm(c1Wb, Abuf, Wst0, Wst1, tid, wr, wc, colq, kg, acc);
    ffn_stageK(c2Wb, 0, Wst0, tid);   // prefetch GEMM2 k=0; covered by h writeback + B2
    float bj[4];
#pragma unroll
    for (int j = 0; j < 4; ++j) bj[j] = c1b[wc * 64 + j * 16 + colq];
#pragma unroll
    for (int i = 0; i < 4; ++i)
#pragma unroll
        for (int r = 0; r < 4; ++r) {
            int m = wr * 64 + i * 16 + rowq + r;
#pragma unroll
            for (int j = 0; j < 4; ++j) {
                int n = wc * 64 + j * 16 + colq;
                float v = fmaxf(acc[i][j][r] + bj[j], 0.0f);
                Abuf[m * 256 + swz(m, n >> 3) * 8 + (n & 7)] = (__bf16)v;
            }
        }
    __syncthreads();   // B2: h visible + c2W k=0 staged (full drain)

    // ---- GEMM2: z = h @ c2W^T + b2 ----
    ffn_gemm(c2Wb, Abuf, Wst0, Wst1, tid, wr, wc, colq, kg, acc);
#pragma unroll
    for (int j = 0; j < 4; ++j) bj[j] = c2b[wc * 64 + j * 16 + colq];
#pragma unroll
    for (int i = 0; i < 4; ++i)
#pragma unroll
        for (int r = 0; r < 4; ++r) {
            int m = wr * 64 + i * 16 + rowq + r;
#pragma unroll
            for (int j = 0; j < 4; ++j) {
                int n = wc * 64 + j * 16 + colq;
                Abuf[m * 256 + swz(m, n >> 3) * 8 + (n & 7)] = (__bf16)(acc[i][j][r] + bj[j]);
            }
        }
    __syncthreads();   // B3: z visible

    // ---- phase 5: s = (z + xn)*keep; LN; outputs ----
    u16x8 zvr[8];
#pragma unroll
    for (int it = 0; it < 8; ++it) {
        int c = tid + it * 512;
        int r = c >> 5, g = c & 31;
        zvr[it] = *(const u16x8*)(Abuf + r * 256 + swz(r, g) * 8);
    }
#pragma unroll
    for (int it = 0; it < 8; ++it) {
        int c = tid + it * 512;
        int r = c >> 5, g = c & 31, col = g * 8;
        float kf = keepv[m0 + r];
        float sv[8];
        float cs = 0.0f, cq = 0.0f;
#pragma unroll
        for (int j = 0; j < 8; ++j) {
            sv[j] = (bf2f(zvr[it][j]) + bf2f(xnreg[it][j])) * kf;
            cs += sv[j]; cq += sv[j] * sv[j];
        }
#pragma unroll
        for (int o = 1; o < 32; o <<= 1) {
            cs += __shfl_xor(cs, o, 32);
            cq += __shfl_xor(cq, o, 32);
        }
        float mean = cs * (1.0f / Hdim);
        float var  = fmaxf(cq * (1.0f / Hdim) - mean * mean, 0.0f);
        float rstd = rsqrtf(var + 1e-8f);
        float4 g0 = *(const float4*)(oG + col), g1 = *(const float4*)(oG + col + 4);
        float4 b0 = *(const float4*)(oB + col), b1 = *(const float4*)(oB + col + 4);
        float gv[8] = {g0.x, g0.y, g0.z, g0.w, g1.x, g1.y, g1.z, g1.w};
        float bv[8] = {b0.x, b0.y, b0.z, b0.w, b1.x, b1.y, b1.z, b1.w};
        size_t off = (size_t)(m0 + r) * Hdim + col;
        float y[8];
#pragma unroll
        for (int j = 0; j < 8; ++j)
            y[j] = (sv[j] - mean) * rstd * gv[j] + bv[j];
        if (outF) {
            float4 o0 = {y[0], y[1], y[2], y[3]};
            float4 o1 = {y[4], y[5], y[6], y[7]};
            *(float4*)(outF + off)     = o0;
            *(float4*)(outF + off + 4) = o1;
        } else {
            u16x8 yb, vb;
            u16x8 tv = *(const u16x8*)(Tbf + off);
#pragma unroll
            for (int j = 0; j < 8; ++j) {
                yb[j] = f2bf(y[j]);
                vb[j] = f2bf(sv[j] + bf2f(tv[j]));
            }
            *(u16x8*)(QxOut + off)  = yb;
            *(u16x8*)(VINout + off) = vb;
        }
    }
}

// ---------------- persistent per-(b,h) attention, 12 waves, b64-aligned slim strides ----------------
// Gates folded into MFMA operands (rank-1): Ks rows pre-scaled by gate(k) at staging,
// Q fragments pre-scaled by gate(q)*lscale at load (A-row = lane&15 = colq -> C row;
// B-col = colq -> C col, per m89 mapping). Inner loop is pure exp2 + mask + cvt + store.
// Softmax denominator via MFMA row-sum: accL += mfma(P_frag, ones).
#define AKS 68
#define AVS 516
#define APS 68
#define ATTN_LDS (512 * AKS * 2 + 64 * AVS * 2 + 192 * APS * 2)
__global__ __launch_bounds__(768, 1)
void attn_mfma_kernel(const unsigned short* __restrict__ Qg,
                      const unsigned short* __restrict__ Kg,
                      const unsigned short* __restrict__ VTg,
                      const float* __restrict__ gates,
                      unsigned short* __restrict__ Ob, int blk) {
    extern __shared__ __align__(16) char smem[];
    __bf16 (*Ks)[AKS]  = (__bf16 (*)[AKS])smem;
    __bf16 (*VTs)[AVS] = (__bf16 (*)[AVS])(smem + 512 * AKS * 2);
    __bf16 (*Ps)[APS]  = (__bf16 (*)[APS])(smem + 512 * AKS * 2 + 64 * AVS * 2);
    int h = blockIdx.x & 3, b = blockIdx.x >> 2;
    int tid = threadIdx.x, lane = tid & 63, w = tid >> 6;
    int colq = lane & 15, grp = lane >> 4;
    int rowq = grp * 4, kq = grp * 8;

    const __bf16 onev = (__bf16)1.0f;
    bf16x8 ones = {onev, onev, onev, onev, onev, onev, onev, onev};

    size_t gbase = (size_t)b * Ldim * 2 + blk;
    size_t baseK = (size_t)b * Ldim * Hdim + h * HD;
    for (int c = tid; c < 4096; c += 768) {
        int r = c >> 3, o = (c & 7) * 8;
        bf8u u;
        u.v8 = *(const bf16x8*)(Kg + baseK + (size_t)r * Hdim + o);
        float gr = gates[gbase + (size_t)r * 2];
#pragma unroll
        for (int j = 0; j < 8; ++j)
            u.v8[j] = (__bf16)((float)u.v8[j] * gr);
        *(bf16x4*)&Ks[r][o]     = u.v4[0];
        *(bf16x4*)&Ks[r][o + 4] = u.v4[1];
    }
    size_t baseV = ((size_t)b * NHEAD + h) * HD * Ldim;
    for (int c = tid; c < 4096; c += 768) {
        int d = c >> 6, k = (c & 63) * 8;
        bf8u u;
        u.v8 = *(const bf16x8*)(VTg + baseV + (size_t)d * Ldim + k);
        *(bf16x4*)&VTs[d][k]     = u.v4[0];
        *(bf16x4*)&VTs[d][k + 4] = u.v4[1];
    }
    __syncthreads();   // the ONLY barrier

    const float lscale = 0.125f * 1.44269504f;
    int gl[3], ng;
    if (w < 4)      { gl[0] = w;     gl[1] = 8 + w;  gl[2] = 28 + w; ng = 3; }
    else if (w < 8) { gl[0] = w;     gl[1] = 8 + w;  gl[2] = 16 + w; ng = 3; }
    else            { gl[0] = 8 + w; gl[1] = 16 + w; gl[2] = 0;      ng = 2; }

    for (int gi = 0; gi < ng; ++gi) {
        int g = gl[gi];
        int q0 = g * 16;
        size_t qrow = (size_t)(b * Ldim + q0 + colq) * Hdim + h * HD;
        float gql = gates[gbase + (size_t)(q0 + colq) * 2] * lscale;
        bf16x8 afq0 = *(const bf16x8*)(Qg + qrow + kq);
        bf16x8 afq1 = *(const bf16x8*)(Qg + qrow + 32 + kq);
#pragma unroll
        for (int j = 0; j < 8; ++j) {
            afq0[j] = (__bf16)((float)afq0[j] * gql);
            afq1[j] = (__bf16)((float)afq1[j] * gql);
        }

        f32x4 accO[4];
        f32x4 accL = (f32x4)(0.0f);
#pragma unroll
        for (int jd = 0; jd < 4; ++jd) accO[jd] = (f32x4)(0.0f);

        int nfull = g >> 2;
        for (int kt = 0; kt <= nfull; ++kt) {
            int k0 = kt * 64;
            bool diag = (kt == nfull);
            f32x4 sv[4];
#pragma unroll
            for (int j = 0; j < 4; ++j) sv[j] = (f32x4)(0.0f);
            __builtin_amdgcn_s_setprio(1);
#pragma unroll
            for (int j = 0; j < 4; ++j) {
                int kr = k0 + j * 16 + colq;
                bf8u b0, b1;
                b0.v4[0] = *(const bf16x4*)&Ks[kr][kq];
                b0.v4[1] = *(const bf16x4*)&Ks[kr][kq + 4];
                b1.v4[0] = *(const bf16x4*)&Ks[kr][32 + kq];
                b1.v4[1] = *(const bf16x4*)&Ks[kr][32 + kq + 4];
                sv[j] = __builtin_amdgcn_mfma_f32_16x16x32_bf16(afq0, b0.v8, sv[j], 0, 0, 0);
                sv[j] = __builtin_amdgcn_mfma_f32_16x16x32_bf16(afq1, b1.v8, sv[j], 0, 0, 0);
            }
            __builtin_amdgcn_s_setprio(0);
#pragma unroll
            for (int r = 0; r < 4; ++r) {
                float p4[4];
                if (diag) {
                    int qg = q0 + rowq + r;
#pragma unroll
                    for (int j = 0; j < 4; ++j) {
                        float e = exp2f(sv[j][r]);
                        p4[j] = (k0 + j * 16 + colq > qg) ? 0.0f : e;
                    }
                } else {
#pragma unroll
                    for (int j = 0; j < 4; ++j)
                        p4[j] = exp2f(sv[j][r]);
                }
#pragma unroll
                for (int j = 0; j < 4; ++j)
                    Ps[w * 16 + rowq + r][j * 16 + colq] = (__bf16)p4[j];
            }
            bf8u a0, a1;
            a0.v4[0] = *(const bf16x4*)&Ps[w * 16 + colq][kq];
            a0.v4[1] = *(const bf16x4*)&Ps[w * 16 + colq][kq + 4];
            a1.v4[0] = *(const bf16x4*)&Ps[w * 16 + colq][32 + kq];
            a1.v4[1] = *(const bf16x4*)&Ps[w * 16 + colq][32 + kq + 4];
            __builtin_amdgcn_s_setprio(1);
            accL = __builtin_amdgcn_mfma_f32_16x16x32_bf16(a0.v8, ones, accL, 0, 0, 0);
            accL = __builtin_amdgcn_mfma_f32_16x16x32_bf16(a1.v8, ones, accL, 0, 0, 0);
#pragma unroll
            for (int jd = 0; jd < 4; ++jd) {
                int vr = jd * 16 + colq;
                bf8u v0, v1;
                v0.v4[0] = *(const bf16x4*)&VTs[vr][k0 + kq];
                v0.v4[1] = *(const bf16x4*)&VTs[vr][k0 + kq + 4];
                v1.v4[0] = *(const bf16x4*)&VTs[vr][k0 + 32 + kq];
                v1.v4[1] = *(const bf16x4*)&VTs[vr][k0 + 32 + kq + 4];
                accO[jd] = __builtin_amdgcn_mfma_f32_16x16x32_bf16(a0.v8, v0.v8, accO[jd], 0, 0, 0);
                accO[jd] = __builtin_amdgcn_mfma_f32_16x16x32_bf16(a1.v8, v1.v8, accO[jd], 0, 0, 0);
            }
            __builtin_amdgcn_s_setprio(0);
        }
#pragma unroll
        for (int r = 0; r < 4; ++r) {
            float inv = 1.0f / accL[r];
#pragma unroll
            for (int jd = 0; jd < 4; ++jd)
                Ob[(size_t)(b * Ldim + q0 + rowq + r) * Hdim + h * HD + jd * 16 + colq] =
                    f2bf(accO[jd][r] * inv);
        }
    }
}

// ---------------- launcher ----------------
extern "C" void kernel_launch(void* const* d_in, const int* in_sizes, int n_in,
                              void* d_out, int out_size, void* d_ws, size_t ws_size,
                              hipStream_t stream) {
    const int*   seqs_data = (const int*)d_in[0];
    const float* seqs      = (const float*)d_in[1];
    const int*   position  = (const int*)d_in[2];
    const float* time_emb  = (const float*)d_in[3];
    const float* pos_table = (const float*)d_in[4];
    const float* gate_W    = (const float*)d_in[5];
    const float* gate_b    = (const float*)d_in[6];
    const float* ln_attn_g = (const float*)d_in[7];
    const float* ln_attn_b = (const float*)d_in[8];
    const float* qW        = (const float*)d_in[9];
    const float* qb        = (const float*)d_in[10];
    const float* kW        = (const float*)d_in[11];
    const float* kb        = (const float*)d_in[12];
    const float* vW        = (const float*)d_in[13];
    const float* vb        = (const float*)d_in[14];
    const float* ln_ffn_g  = (const float*)d_in[15];
    const float* ln_ffn_b  = (const float*)d_in[16];
    const float* c1W       = (const float*)d_in[17];
    const float* c1b       = (const float*)d_in[18];
    const float* c2W       = (const float*)d_in[19];
    const float* c2b       = (const float*)d_in[20];
    const float* last_g    = (const float*)d_in[21];
    const float* last_b    = (const float*)d_in[22];

    size_t BUF = (size_t)NTOK * Hdim;
    float* fws = (float*)d_ws;
    float* GATES = fws;                       // NTOK*2
    float* KEEP  = GATES + (size_t)NTOK * 2;  // NTOK
    unsigned short* bws   = (unsigned short*)(KEEP + NTOK);
    unsigned short* Tbf   = bws;
    unsigned short* QXbf  = Tbf + BUF;        // Q / next-Q (in place)
    unsigned short* VINbf = QXbf + BUF;
    unsigned short* HIDbf = VINbf + BUF;      // (unused, layout kept)
    unsigned short* Qbf   = HIDbf + BUF;
    unsigned short* Kbf   = Qbf + BUF;
    unsigned short* VTbf  = Kbf + BUF;        // V^T [B][NH][HD][L]
    unsigned short* QAbf  = VTbf + BUF;
    unsigned short* Zbf   = QAbf + BUF;       // (unused, layout kept)
    unsigned short* Wbf   = Zbf + BUF;
    size_t WB = (size_t)Hdim * Hdim;
    unsigned short* qWbf  = Wbf;
    unsigned short* kWbf  = Wbf + 2 * WB;
    unsigned short* vWbf  = Wbf + 4 * WB;
    unsigned short* c1Wbf = Wbf + 6 * WB;
    unsigned short* c2Wbf = Wbf + 8 * WB;

    // prep (8192 blocks) + fused castw tail (640 blocks)
    prep_ln_kernel<<<NTOK / 4 + 640, 256, 0, stream>>>(seqs_data, seqs, position, time_emb,
                                                       pos_table, gate_W, gate_b,
                                                       ln_attn_g, ln_attn_b,
                                                       Tbf, QXbf, VINbf, GATES, KEEP,
                                                       qW, kW, vW, c1W, c2W, Wbf);

    dim3 qkvgrid(Hdim / GBN, NTOK / GBM, 3);   // (2, 256, 3)
    for (int i = 0; i < 2; ++i) {
        gemm_qkv_kernel<<<qkvgrid, 256, 0, stream>>>(QXbf, Tbf, VINbf,
                                                     qWbf + i * WB, kWbf + i * WB, vWbf + i * WB,
                                                     qb + i * Hdim, kb + i * Hdim, vb + i * Hdim,
                                                     Qbf, Kbf, VTbf);
        attn_mfma_kernel<<<Bdim * NHEAD, 768, ATTN_LDS, stream>>>(Qbf, Kbf, VTbf, GATES, QAbf, i);
        ffn_kernel<<<NTOK / FBM, 512, FFN_LDS, stream>>>(
            QXbf, QAbf,
            ln_ffn_g + i * Hdim, ln_ffn_b + i * Hdim,
            c1Wbf + i * WB, c1b + i * Hdim,
            c2Wbf + i * WB, c2b + i * Hdim,
            KEEP, Tbf,
            (i == 0) ? ln_attn_g + Hdim : last_g,
            (i == 0) ? ln_attn_b + Hdim : last_b,
            (i == 0) ? nullptr : (float*)d_out,
            QXbf, VINbf);
    }
}